// Round 1
// baseline (232.135 us; speedup 1.0000x reference)
//
#include <hip/hip_runtime.h>
#include <math.h>

typedef short bf16x8 __attribute__((ext_vector_type(8)));
typedef short bf16x4 __attribute__((ext_vector_type(4)));
typedef float floatx4 __attribute__((ext_vector_type(4)));
typedef float floatx2 __attribute__((ext_vector_type(2)));

#define NB   16384   // batch
#define H8   8       // heads
#define ND   256     // D
#define NHD  128     // HD
#define NK   384     // HD + D
#define BM   32      // rows per block
#define NT   512     // threads per block (8 waves)

// ws layout (bytes): wt_hi | wt_lo | wo  (bf16 fragment-packed)
#define WT_ELEMS (H8 * NK * NHD)     // 393216
#define WO_ELEMS (H8 * NHD * ND)     // 262144

__device__ __forceinline__ unsigned short f2bf(float f) {
  unsigned int u = __float_as_uint(f);
  u += 0x7FFFu + ((u >> 16) & 1u);
  return (unsigned short)(u >> 16);
}
__device__ __forceinline__ float bf2f(unsigned short s) {
  return __uint_as_float(((unsigned int)s) << 16);
}

// Pack weights into MFMA B-fragment layout: [head][k/8][n][8] so that a lane's
// 8 consecutive-k values for fixed n are one contiguous 16B load.
__global__ void prep_kernel(const float* __restrict__ tanh_w,
                            const float* __restrict__ out_w,
                            short* __restrict__ wt_hi,
                            short* __restrict__ wt_lo,
                            short* __restrict__ wo) {
  const int total1 = WT_ELEMS;
  const int total2 = WO_ELEMS;
  for (int i = blockIdx.x * blockDim.x + threadIdx.x; i < total1 + total2;
       i += gridDim.x * blockDim.x) {
    if (i < total1) {
      int hh = i / (NK * NHD);
      int rem = i - hh * NK * NHD;
      int k = rem / NHD, n = rem - k * NHD;
      float w = tanh_w[i];
      unsigned short hi = f2bf(w);
      unsigned short lo = f2bf(w - bf2f(hi));
      int dst = hh * (48 * NHD * 8) + (k >> 3) * (NHD * 8) + n * 8 + (k & 7);
      wt_hi[dst] = (short)hi;
      wt_lo[dst] = (short)lo;
    } else {
      int j = i - total1;
      int hh = j / (NHD * ND);
      int rem = j - hh * NHD * ND;
      int k = rem / ND, n = rem - k * ND;
      int dst = hh * (16 * ND * 8) + (k >> 3) * (ND * 8) + n * 8 + (k & 7);
      wo[dst] = (short)f2bf(out_w[j]);
    }
  }
}

// A tile LDS: [BM][392] bf16 (pad 384->392: row stride 784B = 49*16B, 2-way bank alias = free)
#define LDA 392
#define LDNH 136  // 128 + 8 pad

__global__ __launch_bounds__(NT, 4) void gru_main(
    const float* __restrict__ x, const float* __restrict__ h,
    const float* __restrict__ sig_w, const float* __restrict__ sig_b,
    const float* __restrict__ tanh_b, const float* __restrict__ out_b,
    const short* __restrict__ wt_hi, const short* __restrict__ wt_lo,
    const short* __restrict__ wo,
    float* __restrict__ out, float* __restrict__ out_nh) {
  __shared__ __align__(16) short Ahi[BM][LDA];
  __shared__ __align__(16) short Alo[BM][LDA];
  __shared__ __align__(16) short NHL[BM][LDNH];
  __shared__ float gbuf[BM], pbuf[BM];

  const int t = threadIdx.x;
  const int lane = t & 63;
  const int wid = t >> 6;        // 0..7
  const int wrow = wid >> 2;     // 0..1  (16 rows each)
  const int wcol = wid & 3;      // 0..3
  const int ln = lane & 15;
  const int kg = lane >> 4;      // 0..3
  const long rowbase = (long)blockIdx.x * BM;
  const int arow = wrow * 16 + ln;

  // ---- stage x part (cols 128..383) once, hi/lo split ----
#pragma unroll
  for (int i = 0; i < 4; ++i) {
    int idx = i * NT + t;        // 0..2047
    int r = idx >> 6, c4 = idx & 63;
    floatx4 v = *reinterpret_cast<const floatx4*>(x + (rowbase + r) * ND + c4 * 4);
    bf16x4 hi, lo;
#pragma unroll
    for (int j = 0; j < 4; ++j) {
      unsigned short hb = f2bf(v[j]);
      hi[j] = (short)hb;
      lo[j] = (short)f2bf(v[j] - bf2f(hb));
    }
    *reinterpret_cast<bf16x4*>(&Ahi[r][NHD + c4 * 4]) = hi;
    *reinterpret_cast<bf16x4*>(&Alo[r][NHD + c4 * 4]) = lo;
  }

  for (int head = 0; head < H8; ++head) {
    if (head) __syncthreads();   // prev iter's readers done before restage

    // ---- stage h part (cols 0..127), hi/lo split ----
#pragma unroll
    for (int i = 0; i < 2; ++i) {
      int idx = i * NT + t;      // 0..1023
      int r = idx >> 5, c4 = idx & 31;
      floatx4 v = *reinterpret_cast<const floatx4*>(
          h + ((rowbase + r) * H8 + head) * NHD + c4 * 4);
      bf16x4 hi, lo;
#pragma unroll
      for (int j = 0; j < 4; ++j) {
        unsigned short hb = f2bf(v[j]);
        hi[j] = (short)hb;
        lo[j] = (short)f2bf(v[j] - bf2f(hb));
      }
      *reinterpret_cast<bf16x4*>(&Ahi[r][c4 * 4]) = hi;
      *reinterpret_cast<bf16x4*>(&Alo[r][c4 * 4]) = lo;
    }

    // ---- sigmoid dots in full f32 (16 threads per row) ----
    {
      int r = t >> 4, u = t & 15;
      const float* hrow = h + ((rowbase + r) * H8 + head) * NHD;
      const float* xrow = x + (rowbase + r) * ND;
      float a0 = 0.f, a1 = 0.f;
#pragma unroll
      for (int kk = 0; kk < 24; ++kk) {
        int k = u + kk * 16;
        float a = (kk < 8) ? hrow[k] : xrow[k - NHD];
        floatx2 w = *reinterpret_cast<const floatx2*>(sig_w + ((size_t)head * NK + k) * 2);
        a0 += a * w[0];
        a1 += a * w[1];
      }
#pragma unroll
      for (int off = 1; off < 16; off <<= 1) {
        a0 += __shfl_xor(a0, off);
        a1 += __shfl_xor(a1, off);
      }
      if (u == 0) {
        float z0 = a0 + sig_b[head * 2 + 0];
        float z1 = a1 + sig_b[head * 2 + 1];
        gbuf[r] = 1.f / (1.f + expf(-z0));
        pbuf[r] = 1.f / (1.f + expf(-z1));
      }
    }
    __syncthreads();

    // ---- tanh matmul: acc1 = h@Wt[0:128], acc2 = x@Wt[128:384], split-bf16 (3 MFMA) ----
    floatx4 acc1[2] = {{0.f, 0.f, 0.f, 0.f}, {0.f, 0.f, 0.f, 0.f}};
    floatx4 acc2[2] = {{0.f, 0.f, 0.f, 0.f}, {0.f, 0.f, 0.f, 0.f}};
    const size_t wtbase = (size_t)head * (48 * NHD * 8);
#pragma unroll
    for (int ks = 0; ks < 12; ++ks) {
      bf16x8 ahi = *reinterpret_cast<const bf16x8*>(&Ahi[arow][ks * 32 + kg * 8]);
      bf16x8 alo = *reinterpret_cast<const bf16x8*>(&Alo[arow][ks * 32 + kg * 8]);
      floatx4* acc = (ks < 4) ? acc1 : acc2;
#pragma unroll
      for (int cf = 0; cf < 2; ++cf) {
        int n0 = wcol * 32 + cf * 16;
        size_t woff = wtbase + (size_t)(ks * 4 + kg) * (NHD * 8) + (size_t)(n0 + ln) * 8;
        bf16x8 bhi = *reinterpret_cast<const bf16x8*>(wt_hi + woff);
        bf16x8 blo = *reinterpret_cast<const bf16x8*>(wt_lo + woff);
        acc[cf] = __builtin_amdgcn_mfma_f32_16x16x32_bf16(ahi, bhi, acc[cf], 0, 0, 0);
        acc[cf] = __builtin_amdgcn_mfma_f32_16x16x32_bf16(alo, bhi, acc[cf], 0, 0, 0);
        acc[cf] = __builtin_amdgcn_mfma_f32_16x16x32_bf16(ahi, blo, acc[cf], 0, 0, 0);
      }
    }

    // ---- GRU epilogue: s = g*T1 + T2 + b; cand = tanh(s); new_h = h + p*(cand-h) ----
#pragma unroll
    for (int cf = 0; cf < 2; ++cf) {
      int col = wcol * 32 + cf * 16 + ln;
      float tb = tanh_b[head * NHD + col];
#pragma unroll
      for (int j = 0; j < 4; ++j) {
        int r = wrow * 16 + kg * 4 + j;
        float g = gbuf[r], p = pbuf[r];
        float s = g * acc1[cf][j] + acc2[cf][j] + tb;
        float cand = tanhf(s);
        float hv = bf2f((unsigned short)Ahi[r][col]) + bf2f((unsigned short)Alo[r][col]);
        float nh = hv + p * (cand - hv);
        out_nh[((rowbase + r) * H8 + head) * NHD + col] = nh;
        NHL[r][col] = (short)f2bf(nh);
      }
    }
    __syncthreads();

    // ---- out matmul: new_h @ out_w (plain bf16) ----
    floatx4 acc3[4] = {{0.f, 0.f, 0.f, 0.f}, {0.f, 0.f, 0.f, 0.f},
                       {0.f, 0.f, 0.f, 0.f}, {0.f, 0.f, 0.f, 0.f}};
    const size_t wobase = (size_t)head * (16 * ND * 8);
#pragma unroll
    for (int ks = 0; ks < 4; ++ks) {
      bf16x8 a = *reinterpret_cast<const bf16x8*>(&NHL[arow][ks * 32 + kg * 8]);
#pragma unroll
      for (int cf = 0; cf < 4; ++cf) {
        int n0 = wcol * 64 + cf * 16;
        size_t woff = wobase + (size_t)(ks * 4 + kg) * (ND * 8) + (size_t)(n0 + ln) * 8;
        bf16x8 b = *reinterpret_cast<const bf16x8*>(wo + woff);
        acc3[cf] = __builtin_amdgcn_mfma_f32_16x16x32_bf16(a, b, acc3[cf], 0, 0, 0);
      }
    }
#pragma unroll
    for (int cf = 0; cf < 4; ++cf) {
      int col = wcol * 64 + cf * 16 + ln;
      float ob = out_b[head * ND + col];
#pragma unroll
      for (int j = 0; j < 4; ++j) {
        int r = wrow * 16 + kg * 4 + j;
        out[((rowbase + r) * H8 + head) * ND + col] = acc3[cf][j] + ob;
      }
    }
  }
}

extern "C" void kernel_launch(void* const* d_in, const int* in_sizes, int n_in,
                              void* d_out, int out_size, void* d_ws, size_t ws_size,
                              hipStream_t stream) {
  (void)in_sizes; (void)n_in; (void)out_size; (void)ws_size;
  const float* x      = (const float*)d_in[0];
  const float* h      = (const float*)d_in[1];
  const float* sig_w  = (const float*)d_in[2];
  const float* sig_b  = (const float*)d_in[3];
  const float* tanh_w = (const float*)d_in[4];
  const float* tanh_b = (const float*)d_in[5];
  const float* out_w  = (const float*)d_in[6];
  const float* out_b  = (const float*)d_in[7];

  float* out = (float*)d_out;
  float* out_nh = out + (size_t)NB * H8 * ND;

  short* wt_hi = (short*)d_ws;
  short* wt_lo = wt_hi + WT_ELEMS;
  short* wo    = wt_lo + WT_ELEMS;

  hipLaunchKernelGGL(prep_kernel, dim3(512), dim3(256), 0, stream,
                     tanh_w, out_w, wt_hi, wt_lo, wo);
  hipLaunchKernelGGL(gru_main, dim3(NB / BM), dim3(NT), 0, stream,
                     x, h, sig_w, sig_b, tanh_b, out_b, wt_hi, wt_lo, wo,
                     out, out_nh);
}

// Round 2
// 149.109 us; speedup vs baseline: 1.5568x; 1.5568x over previous
//
#include <hip/hip_runtime.h>
#include <math.h>

typedef short bf16x8 __attribute__((ext_vector_type(8)));
typedef short bf16x4 __attribute__((ext_vector_type(4)));
typedef float floatx4 __attribute__((ext_vector_type(4)));
typedef float floatx2 __attribute__((ext_vector_type(2)));

#define NB   16384   // batch
#define H8   8       // heads
#define ND   256     // D
#define NHD  128     // HD
#define NK   384     // HD + D
#define BM   32      // rows per block
#define NT   512     // threads per block (8 waves)

#define WT_ELEMS (H8 * NK * NHD)     // 393216
#define WO_ELEMS (H8 * NHD * ND)     // 262144

__device__ __forceinline__ unsigned short f2bf(float f) {
  unsigned int u = __float_as_uint(f);
  u += 0x7FFFu + ((u >> 16) & 1u);
  return (unsigned short)(u >> 16);
}
__device__ __forceinline__ float bf2f(unsigned short s) {
  return __uint_as_float(((unsigned int)s) << 16);
}

// Pack weights into MFMA B-fragment layout: [head][k/8][n][8]
__global__ void prep_kernel(const float* __restrict__ tanh_w,
                            const float* __restrict__ out_w,
                            short* __restrict__ wt_hi,
                            short* __restrict__ wt_lo,
                            short* __restrict__ wo) {
  const int total1 = WT_ELEMS;
  const int total2 = WO_ELEMS;
  for (int i = blockIdx.x * blockDim.x + threadIdx.x; i < total1 + total2;
       i += gridDim.x * blockDim.x) {
    if (i < total1) {
      int hh = i / (NK * NHD);
      int rem = i - hh * NK * NHD;
      int k = rem / NHD, n = rem - k * NHD;
      float w = tanh_w[i];
      unsigned short hi = f2bf(w);
      unsigned short lo = f2bf(w - bf2f(hi));
      int dst = hh * (48 * NHD * 8) + (k >> 3) * (NHD * 8) + n * 8 + (k & 7);
      wt_hi[dst] = (short)hi;
      wt_lo[dst] = (short)lo;
    } else {
      int j = i - total1;
      int hh = j / (NHD * ND);
      int rem = j - hh * NHD * ND;
      int k = rem / ND, n = rem - k * ND;
      int dst = hh * (16 * ND * 8) + (k >> 3) * (ND * 8) + n * 8 + (k & 7);
      wo[dst] = (short)f2bf(out_w[j]);
    }
  }
}

#define LDA 392   // 384+8 pad (row stride 784B: 2-way bank alias = free)
#define LDNH 136  // 128+8 pad

__global__ __launch_bounds__(NT, 4) void gru_main(
    const float* __restrict__ x, const float* __restrict__ h,
    const float* __restrict__ sig_w, const float* __restrict__ sig_b,
    const float* __restrict__ tanh_b, const float* __restrict__ out_b,
    const short* __restrict__ wt_hi, const short* __restrict__ wt_lo,
    const short* __restrict__ wo,
    float* __restrict__ out, float* __restrict__ out_nh) {
  __shared__ __align__(16) short Ahi[BM][LDA];
  __shared__ __align__(16) short Alo[BM][LDA];
  __shared__ __align__(16) short NHL[BM][LDNH];
  __shared__ floatx2 swl[NK];
  __shared__ float gbuf[BM], pbuf[BM];

  const int t = threadIdx.x;
  const int lane = t & 63;
  const int wid = t >> 6;        // 0..7
  const int wrow = wid >> 2;     // 0..1  (16 rows each)
  const int wcol = wid & 3;      // 0..3
  const int ln = lane & 15;
  const int kg = lane >> 4;      // 0..3
  const int head = blockIdx.x & 7;
  const long rowbase = (long)(blockIdx.x >> 3) * BM;
  const int arow = wrow * 16 + ln;

  // ---- stage x part (cols 128..383), hi/lo split ----
#pragma unroll
  for (int i = 0; i < 4; ++i) {
    int idx = i * NT + t;        // 0..2047
    int r = idx >> 6, c4 = idx & 63;
    floatx4 v = *reinterpret_cast<const floatx4*>(x + (rowbase + r) * ND + c4 * 4);
    bf16x4 hi, lo;
#pragma unroll
    for (int j = 0; j < 4; ++j) {
      unsigned short hb = f2bf(v[j]);
      hi[j] = (short)hb;
      lo[j] = (short)f2bf(v[j] - bf2f(hb));
    }
    *reinterpret_cast<bf16x4*>(&Ahi[r][NHD + c4 * 4]) = hi;
    *reinterpret_cast<bf16x4*>(&Alo[r][NHD + c4 * 4]) = lo;
  }

  // ---- stage h part (cols 0..127), hi/lo split ----
#pragma unroll
  for (int i = 0; i < 2; ++i) {
    int idx = i * NT + t;        // 0..1023
    int r = idx >> 5, c4 = idx & 31;
    floatx4 v = *reinterpret_cast<const floatx4*>(
        h + ((rowbase + r) * H8 + head) * NHD + c4 * 4);
    bf16x4 hi, lo;
#pragma unroll
    for (int j = 0; j < 4; ++j) {
      unsigned short hb = f2bf(v[j]);
      hi[j] = (short)hb;
      lo[j] = (short)f2bf(v[j] - bf2f(hb));
    }
    *reinterpret_cast<bf16x4*>(&Ahi[r][c4 * 4]) = hi;
    *reinterpret_cast<bf16x4*>(&Alo[r][c4 * 4]) = lo;
  }

  // ---- stage sig_w for this head ----
  if (t < NK)
    swl[t] = *reinterpret_cast<const floatx2*>(sig_w + ((size_t)head * NK + t) * 2);

  __syncthreads();

  // ---- sigmoid dots from LDS (16 threads per row) ----
  {
    int r = t >> 4, u = t & 15;
    float a0 = 0.f, a1 = 0.f;
#pragma unroll
    for (int kk = 0; kk < 24; ++kk) {
      int k = u + kk * 16;
      float a = bf2f((unsigned short)Ahi[r][k]) + bf2f((unsigned short)Alo[r][k]);
      floatx2 w = swl[k];
      a0 += a * w[0];
      a1 += a * w[1];
    }
#pragma unroll
    for (int off = 1; off < 16; off <<= 1) {
      a0 += __shfl_xor(a0, off);
      a1 += __shfl_xor(a1, off);
    }
    if (u == 0) {
      float z0 = a0 + sig_b[head * 2 + 0];
      float z1 = a1 + sig_b[head * 2 + 1];
      gbuf[r] = 1.f / (1.f + expf(-z0));
      pbuf[r] = 1.f / (1.f + expf(-z1));
    }
  }

  // ---- tanh matmul: acc1 = h@Wt[0:128], acc2 = x@Wt[128:384], split-bf16 ----
  floatx4 acc1[2] = {{0.f, 0.f, 0.f, 0.f}, {0.f, 0.f, 0.f, 0.f}};
  floatx4 acc2[2] = {{0.f, 0.f, 0.f, 0.f}, {0.f, 0.f, 0.f, 0.f}};
  const size_t wtbase = (size_t)head * (48 * NHD * 8);
#pragma unroll
  for (int ks = 0; ks < 12; ++ks) {
    bf16x8 ahi = *reinterpret_cast<const bf16x8*>(&Ahi[arow][ks * 32 + kg * 8]);
    bf16x8 alo = *reinterpret_cast<const bf16x8*>(&Alo[arow][ks * 32 + kg * 8]);
    floatx4* acc = (ks < 4) ? acc1 : acc2;
#pragma unroll
    for (int cf = 0; cf < 2; ++cf) {
      int n0 = wcol * 32 + cf * 16;
      size_t woff = wtbase + (size_t)(ks * 4 + kg) * (NHD * 8) + (size_t)(n0 + ln) * 8;
      bf16x8 bhi = *reinterpret_cast<const bf16x8*>(wt_hi + woff);
      bf16x8 blo = *reinterpret_cast<const bf16x8*>(wt_lo + woff);
      acc[cf] = __builtin_amdgcn_mfma_f32_16x16x32_bf16(ahi, bhi, acc[cf], 0, 0, 0);
      acc[cf] = __builtin_amdgcn_mfma_f32_16x16x32_bf16(alo, bhi, acc[cf], 0, 0, 0);
      acc[cf] = __builtin_amdgcn_mfma_f32_16x16x32_bf16(ahi, blo, acc[cf], 0, 0, 0);
    }
  }
  __syncthreads();   // gbuf/pbuf visible; Ahi/Alo reads in epilogue still valid

  // ---- GRU epilogue ----
#pragma unroll
  for (int cf = 0; cf < 2; ++cf) {
    int col = wcol * 32 + cf * 16 + ln;
    float tb = tanh_b[head * NHD + col];
#pragma unroll
    for (int j = 0; j < 4; ++j) {
      int r = wrow * 16 + kg * 4 + j;
      float g = gbuf[r], p = pbuf[r];
      float s = g * acc1[cf][j] + acc2[cf][j] + tb;
      float cand = tanhf(s);
      float hv = bf2f((unsigned short)Ahi[r][col]) + bf2f((unsigned short)Alo[r][col]);
      float nh = hv + p * (cand - hv);
      out_nh[((rowbase + r) * H8 + head) * NHD + col] = nh;
      NHL[r][col] = (short)f2bf(nh);
    }
  }
  __syncthreads();

  // ---- out matmul: new_h @ out_w (plain bf16) ----
  floatx4 acc3[4] = {{0.f, 0.f, 0.f, 0.f}, {0.f, 0.f, 0.f, 0.f},
                     {0.f, 0.f, 0.f, 0.f}, {0.f, 0.f, 0.f, 0.f}};
  const size_t wobase = (size_t)head * (16 * ND * 8);
#pragma unroll
  for (int ks = 0; ks < 4; ++ks) {
    bf16x8 a = *reinterpret_cast<const bf16x8*>(&NHL[arow][ks * 32 + kg * 8]);
#pragma unroll
    for (int cf = 0; cf < 4; ++cf) {
      int n0 = wcol * 64 + cf * 16;
      size_t woff = wobase + (size_t)(ks * 4 + kg) * (ND * 8) + (size_t)(n0 + ln) * 8;
      bf16x8 b = *reinterpret_cast<const bf16x8*>(wo + woff);
      acc3[cf] = __builtin_amdgcn_mfma_f32_16x16x32_bf16(a, b, acc3[cf], 0, 0, 0);
    }
  }
#pragma unroll
  for (int cf = 0; cf < 4; ++cf) {
    int col = wcol * 64 + cf * 16 + ln;
    float ob = out_b[head * ND + col];
#pragma unroll
    for (int j = 0; j < 4; ++j) {
      int r = wrow * 16 + kg * 4 + j;
      out[((rowbase + r) * H8 + head) * ND + col] = acc3[cf][j] + ob;
    }
  }
}

extern "C" void kernel_launch(void* const* d_in, const int* in_sizes, int n_in,
                              void* d_out, int out_size, void* d_ws, size_t ws_size,
                              hipStream_t stream) {
  (void)in_sizes; (void)n_in; (void)out_size; (void)ws_size;
  const float* x      = (const float*)d_in[0];
  const float* h      = (const float*)d_in[1];
  const float* sig_w  = (const float*)d_in[2];
  const float* sig_b  = (const float*)d_in[3];
  const float* tanh_w = (const float*)d_in[4];
  const float* tanh_b = (const float*)d_in[5];
  const float* out_w  = (const float*)d_in[6];
  const float* out_b  = (const float*)d_in[7];

  float* out = (float*)d_out;
  float* out_nh = out + (size_t)NB * H8 * ND;

  short* wt_hi = (short*)d_ws;
  short* wt_lo = wt_hi + WT_ELEMS;
  short* wo    = wt_lo + WT_ELEMS;

  hipLaunchKernelGGL(prep_kernel, dim3(512), dim3(256), 0, stream,
                     tanh_w, out_w, wt_hi, wt_lo, wo);
  hipLaunchKernelGGL(gru_main, dim3((NB / BM) * H8), dim3(NT), 0, stream,
                     x, h, sig_w, sig_b, tanh_b, out_b, wt_hi, wt_lo, wo,
                     out, out_nh);
}

// Round 3
// 145.952 us; speedup vs baseline: 1.5905x; 1.0216x over previous
//
#include <hip/hip_runtime.h>
#include <math.h>

typedef short bf16x8 __attribute__((ext_vector_type(8)));
typedef short bf16x4 __attribute__((ext_vector_type(4)));
typedef float floatx4 __attribute__((ext_vector_type(4)));
typedef float floatx2 __attribute__((ext_vector_type(2)));
typedef float floatx16 __attribute__((ext_vector_type(16)));

#define NB   16384
#define H8   8
#define ND   256
#define NHD  128
#define NK   384

__device__ __forceinline__ unsigned short f2bf(float f) {
  unsigned int u = __float_as_uint(f);
  u += 0x7FFFu + ((u >> 16) & 1u);
  return (unsigned short)(u >> 16);
}
__device__ __forceinline__ float bf2f(unsigned short s) {
  return __uint_as_float(((unsigned int)s) << 16);
}

// ================= NEW PATH (32x32x16 fragment-packed) =================
// sizes in shorts
#define WTP (H8 * 24 * 4 * 512)   // 393216 tanh_w frags (hi and lo arrays)
#define WSP (H8 * 24 * 512)       // 98304 sig_w frags (cols 0,1 real)
#define WOP (H8 * 8 * 8 * 512)    // 262144 out_w frags
#define XFP (NB * ND)             // 4194304 x frags (hi and lo)
#define WS_NEED3 ((size_t)(2 * WTP + 2 * WSP + WOP + 2 * XFP) * 2)

// Fragment layouts (bf16, 512 shorts per 64-lane tile):
//  wtp[head][ks0..23][ct0..3][l][8] : B[k=ks*16+(l>>5)*8+j][n=ct*32+(l&31)]
//  wsp[head][ks0..23][l][8]         : sig cols n=(l&31)<2 else 0
//  wop[head][ks0..7][ct0..7][l][8]  : out_w B-frags
//  xf[b>>5][xks0..15][l][8]         : A[row=(b&31)][k... c=xks*16+(l>>5)*8+j]
__global__ void prep3(const float* __restrict__ tanh_w,
                      const float* __restrict__ sig_w,
                      const float* __restrict__ out_w,
                      const float* __restrict__ x,
                      short* __restrict__ wtp_hi, short* __restrict__ wtp_lo,
                      short* __restrict__ wsp_hi, short* __restrict__ wsp_lo,
                      short* __restrict__ wop,
                      short* __restrict__ xfh, short* __restrict__ xfl) {
  const int T1 = WTP, T2 = T1 + WSP, T3 = T2 + WOP, T4 = T3 + XFP;
  for (int i = blockIdx.x * blockDim.x + threadIdx.x; i < T4;
       i += gridDim.x * blockDim.x) {
    if (i < T1) {
      int j = i & 7, l = (i >> 3) & 63, ct = (i >> 9) & 3;
      int q2 = i >> 11;
      int ks = q2 % 24, head = q2 / 24;
      int k = ks * 16 + (l >> 5) * 8 + j, n = ct * 32 + (l & 31);
      float w = tanh_w[((size_t)head * NK + k) * NHD + n];
      unsigned short hi = f2bf(w);
      wtp_hi[i] = (short)hi;
      wtp_lo[i] = (short)f2bf(w - bf2f(hi));
    } else if (i < T2) {
      int i2 = i - T1;
      int j = i2 & 7, l = (i2 >> 3) & 63;
      int q = i2 >> 9;
      int ks = q % 24, head = q / 24;
      int k = ks * 16 + (l >> 5) * 8 + j, n = l & 31;
      float w = (n < 2) ? sig_w[((size_t)head * NK + k) * 2 + n] : 0.f;
      unsigned short hi = f2bf(w);
      wsp_hi[i2] = (short)hi;
      wsp_lo[i2] = (short)f2bf(w - bf2f(hi));
    } else if (i < T3) {
      int i3 = i - T2;
      int j = i3 & 7, l = (i3 >> 3) & 63;
      int q = i3 >> 9;
      int ct = q & 7, q2 = q >> 3;
      int ks = q2 & 7, head = q2 >> 3;
      int k = ks * 16 + (l >> 5) * 8 + j, n = ct * 32 + (l & 31);
      wop[i3] = (short)f2bf(out_w[((size_t)head * NHD + k) * ND + n]);
    } else {
      int i4 = i - T3;
      int b = i4 >> 8, c = i4 & 255;
      float v = x[i4];
      int dst = ((b >> 5) * 16 + (c >> 4)) * 512 +
                (((c >> 3) & 1) * 32 + (b & 31)) * 8 + (c & 7);
      unsigned short hi = f2bf(v);
      xfh[dst] = (short)hi;
      xfl[dst] = (short)f2bf(v - bf2f(hi));
    }
  }
}

#define BM3 64

__global__ __launch_bounds__(512, 4) void gru3(
    const float* __restrict__ h, const float* __restrict__ sig_b,
    const float* __restrict__ tanh_b, const float* __restrict__ out_b,
    const short* __restrict__ wtp_hi, const short* __restrict__ wtp_lo,
    const short* __restrict__ wsp_hi, const short* __restrict__ wsp_lo,
    const short* __restrict__ wop,
    const short* __restrict__ xfh, const short* __restrict__ xfl,
    float* __restrict__ out, float* __restrict__ out_nh) {
  __shared__ __align__(16) short AhH[2 * 8 * 512];   // 16 KB, FL32 h hi
  __shared__ __align__(16) short AhL[2 * 8 * 512];   // 16 KB
  __shared__ __align__(16) short NHF[2 * 8 * 512];   // 16 KB new_h frags
  __shared__ float sig_part[2 * 4 * 2 * 32];         // [rg][cq][col][row]
  __shared__ float gbuf[BM3], pbuf[BM3];

  const int t = threadIdx.x;
  const int lane = t & 63;
  const int wid = t >> 6;
  const int rg = wid >> 2;        // 0..1 row-group of 32
  const int cq = wid & 3;         // 0..3 col-quad of 32
  const int l31 = lane & 31;
  const int lh = lane >> 5;       // 0/1
  const int head = blockIdx.x & 7;
  const long rowbase = (long)(blockIdx.x >> 3) * BM3;
  const int grg = (int)(blockIdx.x >> 3) * 2;   // global rowgroup32 base

  // ---- stage h into FL32 LDS (hi/lo), lane-linear writes ----
#pragma unroll
  for (int it = 0; it < 2; ++it) {
    int cidx = it * 512 + t;          // 0..1023 chunks of 8 elems
    int srg = cidx >> 9, sks = (cidx >> 6) & 7, sl = cidx & 63;
    int r = srg * 32 + (sl & 31);
    int k = sks * 16 + (sl >> 5) * 8;
    const float* hp = h + ((rowbase + r) * H8 + head) * NHD + k;
    floatx4 v0 = *reinterpret_cast<const floatx4*>(hp);
    floatx4 v1 = *reinterpret_cast<const floatx4*>(hp + 4);
    bf16x8 hi8, lo8;
#pragma unroll
    for (int j = 0; j < 4; ++j) {
      unsigned short hb = f2bf(v0[j]);
      hi8[j] = (short)hb; lo8[j] = (short)f2bf(v0[j] - bf2f(hb));
      unsigned short hb2 = f2bf(v1[j]);
      hi8[4 + j] = (short)hb2; lo8[4 + j] = (short)f2bf(v1[j] - bf2f(hb2));
    }
    *reinterpret_cast<bf16x8*>(&AhH[cidx * 8]) = hi8;
    *reinterpret_cast<bf16x8*>(&AhL[cidx * 8]) = lo8;
  }
  __syncthreads();

  // ---- tanh (+sig partial) MFMA: acc1 = h-part, acc2 = x-part ----
  floatx16 acc1, acc2, accS;
#pragma unroll
  for (int z = 0; z < 16; ++z) { acc1[z] = 0.f; acc2[z] = 0.f; accS[z] = 0.f; }

  // h-part: ks 0..7, A from LDS
#pragma unroll
  for (int ks = 0; ks < 8; ++ks) {
    bf16x8 ah = *reinterpret_cast<const bf16x8*>(&AhH[((rg * 8 + ks) * 64 + lane) * 8]);
    bf16x8 al = *reinterpret_cast<const bf16x8*>(&AhL[((rg * 8 + ks) * 64 + lane) * 8]);
    size_t boff = (((size_t)(head * 24 + ks) * 4 + cq) * 64 + lane) * 8;
    bf16x8 bh = *reinterpret_cast<const bf16x8*>(wtp_hi + boff);
    bf16x8 bl = *reinterpret_cast<const bf16x8*>(wtp_lo + boff);
    acc1 = __builtin_amdgcn_mfma_f32_32x32x16_bf16(ah, bh, acc1, 0, 0, 0);
    acc1 = __builtin_amdgcn_mfma_f32_32x32x16_bf16(al, bh, acc1, 0, 0, 0);
    acc1 = __builtin_amdgcn_mfma_f32_32x32x16_bf16(ah, bl, acc1, 0, 0, 0);
    if (ks / 6 == cq) {
      size_t soff = ((size_t)(head * 24 + ks) * 64 + lane) * 8;
      bf16x8 sh = *reinterpret_cast<const bf16x8*>(wsp_hi + soff);
      bf16x8 sl2 = *reinterpret_cast<const bf16x8*>(wsp_lo + soff);
      accS = __builtin_amdgcn_mfma_f32_32x32x16_bf16(ah, sh, accS, 0, 0, 0);
      accS = __builtin_amdgcn_mfma_f32_32x32x16_bf16(al, sh, accS, 0, 0, 0);
      accS = __builtin_amdgcn_mfma_f32_32x32x16_bf16(ah, sl2, accS, 0, 0, 0);
    }
  }
  // x-part: ks 8..23, A straight from pre-packed global (L2/L3)
#pragma unroll
  for (int xks = 0; xks < 16; ++xks) {
    int ks = 8 + xks;
    size_t aoff = ((size_t)((grg + rg) * 16 + xks) * 64 + lane) * 8;
    bf16x8 ah = *reinterpret_cast<const bf16x8*>(xfh + aoff);
    bf16x8 al = *reinterpret_cast<const bf16x8*>(xfl + aoff);
    size_t boff = (((size_t)(head * 24 + ks) * 4 + cq) * 64 + lane) * 8;
    bf16x8 bh = *reinterpret_cast<const bf16x8*>(wtp_hi + boff);
    bf16x8 bl = *reinterpret_cast<const bf16x8*>(wtp_lo + boff);
    acc2 = __builtin_amdgcn_mfma_f32_32x32x16_bf16(ah, bh, acc2, 0, 0, 0);
    acc2 = __builtin_amdgcn_mfma_f32_32x32x16_bf16(al, bh, acc2, 0, 0, 0);
    acc2 = __builtin_amdgcn_mfma_f32_32x32x16_bf16(ah, bl, acc2, 0, 0, 0);
    if (ks / 6 == cq) {
      size_t soff = ((size_t)(head * 24 + ks) * 64 + lane) * 8;
      bf16x8 sh = *reinterpret_cast<const bf16x8*>(wsp_hi + soff);
      bf16x8 sl2 = *reinterpret_cast<const bf16x8*>(wsp_lo + soff);
      accS = __builtin_amdgcn_mfma_f32_32x32x16_bf16(ah, sh, accS, 0, 0, 0);
      accS = __builtin_amdgcn_mfma_f32_32x32x16_bf16(al, sh, accS, 0, 0, 0);
      accS = __builtin_amdgcn_mfma_f32_32x32x16_bf16(ah, sl2, accS, 0, 0, 0);
    }
  }

  // ---- sig partials -> LDS ----
  if (l31 < 2) {
#pragma unroll
    for (int reg = 0; reg < 16; ++reg) {
      int row = (reg & 3) + 8 * (reg >> 2) + 4 * lh;
      sig_part[((rg * 4 + cq) * 2 + l31) * 32 + row] = accS[reg];
    }
  }
  __syncthreads();
  if (t < 128) {
    int r = t >> 1, col = t & 1;
    int rg2 = r >> 5, rr = r & 31;
    float z = sig_part[((rg2 * 4 + 0) * 2 + col) * 32 + rr] +
              sig_part[((rg2 * 4 + 1) * 2 + col) * 32 + rr] +
              sig_part[((rg2 * 4 + 2) * 2 + col) * 32 + rr] +
              sig_part[((rg2 * 4 + 3) * 2 + col) * 32 + rr] +
              sig_b[head * 2 + col];
    float s = 1.f / (1.f + expf(-z));
    if (col == 0) gbuf[r] = s; else pbuf[r] = s;
  }
  __syncthreads();

  // ---- GRU epilogue ----
  const int col = cq * 32 + l31;
  const float tb = tanh_b[head * NHD + col];
#pragma unroll
  for (int reg = 0; reg < 16; ++reg) {
    int rr32 = (reg & 3) + 8 * (reg >> 2) + 4 * lh;
    int r = rg * 32 + rr32;
    float g = gbuf[r], p = pbuf[r];
    float s = g * acc1[reg] + acc2[reg] + tb;
    float cand = tanhf(s);
    int el = ((rg * 8 + (col >> 4)) * 64 + ((l31 >> 3) & 1) * 32 + rr32) * 8 + (col & 7);
    float hv = bf2f((unsigned short)AhH[el]) + bf2f((unsigned short)AhL[el]);
    float nh = hv + p * (cand - hv);
    out_nh[((rowbase + r) * H8 + head) * NHD + col] = nh;
    NHF[el] = (short)f2bf(nh);
  }
  __syncthreads();

  // ---- out matmul ----
  floatx16 acc3a, acc3b;
#pragma unroll
  for (int z = 0; z < 16; ++z) { acc3a[z] = 0.f; acc3b[z] = 0.f; }
#pragma unroll
  for (int ks = 0; ks < 8; ++ks) {
    bf16x8 a = *reinterpret_cast<const bf16x8*>(&NHF[((rg * 8 + ks) * 64 + lane) * 8]);
    size_t b0 = (((size_t)(head * 8 + ks) * 8 + cq * 2) * 64 + lane) * 8;
    bf16x8 w0 = *reinterpret_cast<const bf16x8*>(wop + b0);
    bf16x8 w1 = *reinterpret_cast<const bf16x8*>(wop + b0 + 512);
    acc3a = __builtin_amdgcn_mfma_f32_32x32x16_bf16(a, w0, acc3a, 0, 0, 0);
    acc3b = __builtin_amdgcn_mfma_f32_32x32x16_bf16(a, w1, acc3b, 0, 0, 0);
  }
  const float ob0 = out_b[head * ND + cq * 64 + l31];
  const float ob1 = out_b[head * ND + cq * 64 + 32 + l31];
#pragma unroll
  for (int reg = 0; reg < 16; ++reg) {
    int r = rg * 32 + (reg & 3) + 8 * (reg >> 2) + 4 * lh;
    long obase = ((rowbase + r) * H8 + head) * ND;
    out[obase + cq * 64 + l31] = acc3a[reg] + ob0;
    out[obase + cq * 64 + 32 + l31] = acc3b[reg] + ob1;
  }
}

// ================= FALLBACK PATH (round-2 kernels, used if ws too small) ===
#define WT_ELEMS (H8 * NK * NHD)
#define WO_ELEMS (H8 * NHD * ND)

__global__ void prep_kernel(const float* __restrict__ tanh_w,
                            const float* __restrict__ out_w,
                            short* __restrict__ wt_hi,
                            short* __restrict__ wt_lo,
                            short* __restrict__ wo) {
  const int total1 = WT_ELEMS;
  const int total2 = WO_ELEMS;
  for (int i = blockIdx.x * blockDim.x + threadIdx.x; i < total1 + total2;
       i += gridDim.x * blockDim.x) {
    if (i < total1) {
      int hh = i / (NK * NHD);
      int rem = i - hh * NK * NHD;
      int k = rem / NHD, n = rem - k * NHD;
      float w = tanh_w[i];
      unsigned short hi = f2bf(w);
      unsigned short lo = f2bf(w - bf2f(hi));
      int dst = hh * (48 * NHD * 8) + (k >> 3) * (NHD * 8) + n * 8 + (k & 7);
      wt_hi[dst] = (short)hi;
      wt_lo[dst] = (short)lo;
    } else {
      int j = i - total1;
      int hh = j / (NHD * ND);
      int rem = j - hh * NHD * ND;
      int k = rem / ND, n = rem - k * ND;
      int dst = hh * (16 * ND * 8) + (k >> 3) * (ND * 8) + n * 8 + (k & 7);
      wo[dst] = (short)f2bf(out_w[j]);
    }
  }
}

#define BM   32
#define NT   512
#define LDA 392
#define LDNH 136

__global__ __launch_bounds__(NT, 4) void gru_main(
    const float* __restrict__ x, const float* __restrict__ h,
    const float* __restrict__ sig_w, const float* __restrict__ sig_b,
    const float* __restrict__ tanh_b, const float* __restrict__ out_b,
    const short* __restrict__ wt_hi, const short* __restrict__ wt_lo,
    const short* __restrict__ wo,
    float* __restrict__ out, float* __restrict__ out_nh) {
  __shared__ __align__(16) short Ahi[BM][LDA];
  __shared__ __align__(16) short Alo[BM][LDA];
  __shared__ __align__(16) short NHL[BM][LDNH];
  __shared__ floatx2 swl[NK];
  __shared__ float gbuf[BM], pbuf[BM];

  const int t = threadIdx.x;
  const int lane = t & 63;
  const int wid = t >> 6;
  const int wrow = wid >> 2;
  const int wcol = wid & 3;
  const int ln = lane & 15;
  const int kg = lane >> 4;
  const int head = blockIdx.x & 7;
  const long rowbase = (long)(blockIdx.x >> 3) * BM;
  const int arow = wrow * 16 + ln;

#pragma unroll
  for (int i = 0; i < 4; ++i) {
    int idx = i * NT + t;
    int r = idx >> 6, c4 = idx & 63;
    floatx4 v = *reinterpret_cast<const floatx4*>(x + (rowbase + r) * ND + c4 * 4);
    bf16x4 hi, lo;
#pragma unroll
    for (int j = 0; j < 4; ++j) {
      unsigned short hb = f2bf(v[j]);
      hi[j] = (short)hb;
      lo[j] = (short)f2bf(v[j] - bf2f(hb));
    }
    *reinterpret_cast<bf16x4*>(&Ahi[r][NHD + c4 * 4]) = hi;
    *reinterpret_cast<bf16x4*>(&Alo[r][NHD + c4 * 4]) = lo;
  }
#pragma unroll
  for (int i = 0; i < 2; ++i) {
    int idx = i * NT + t;
    int r = idx >> 5, c4 = idx & 31;
    floatx4 v = *reinterpret_cast<const floatx4*>(
        h + ((rowbase + r) * H8 + head) * NHD + c4 * 4);
    bf16x4 hi, lo;
#pragma unroll
    for (int j = 0; j < 4; ++j) {
      unsigned short hb = f2bf(v[j]);
      hi[j] = (short)hb;
      lo[j] = (short)f2bf(v[j] - bf2f(hb));
    }
    *reinterpret_cast<bf16x4*>(&Ahi[r][c4 * 4]) = hi;
    *reinterpret_cast<bf16x4*>(&Alo[r][c4 * 4]) = lo;
  }
  if (t < NK)
    swl[t] = *reinterpret_cast<const floatx2*>(sig_w + ((size_t)head * NK + t) * 2);
  __syncthreads();
  {
    int r = t >> 4, u = t & 15;
    float a0 = 0.f, a1 = 0.f;
#pragma unroll
    for (int kk = 0; kk < 24; ++kk) {
      int k = u + kk * 16;
      float a = bf2f((unsigned short)Ahi[r][k]) + bf2f((unsigned short)Alo[r][k]);
      floatx2 w = swl[k];
      a0 += a * w[0];
      a1 += a * w[1];
    }
#pragma unroll
    for (int off = 1; off < 16; off <<= 1) {
      a0 += __shfl_xor(a0, off);
      a1 += __shfl_xor(a1, off);
    }
    if (u == 0) {
      float z0 = a0 + sig_b[head * 2 + 0];
      float z1 = a1 + sig_b[head * 2 + 1];
      gbuf[r] = 1.f / (1.f + expf(-z0));
      pbuf[r] = 1.f / (1.f + expf(-z1));
    }
  }
  floatx4 acc1[2] = {{0.f, 0.f, 0.f, 0.f}, {0.f, 0.f, 0.f, 0.f}};
  floatx4 acc2[2] = {{0.f, 0.f, 0.f, 0.f}, {0.f, 0.f, 0.f, 0.f}};
  const size_t wtbase = (size_t)head * (48 * NHD * 8);
#pragma unroll
  for (int ks = 0; ks < 12; ++ks) {
    bf16x8 ahi = *reinterpret_cast<const bf16x8*>(&Ahi[arow][ks * 32 + kg * 8]);
    bf16x8 alo = *reinterpret_cast<const bf16x8*>(&Alo[arow][ks * 32 + kg * 8]);
    floatx4* acc = (ks < 4) ? acc1 : acc2;
#pragma unroll
    for (int cf = 0; cf < 2; ++cf) {
      int n0 = wcol * 32 + cf * 16;
      size_t woff = wtbase + (size_t)(ks * 4 + kg) * (NHD * 8) + (size_t)(n0 + ln) * 8;
      bf16x8 bhi = *reinterpret_cast<const bf16x8*>(wt_hi + woff);
      bf16x8 blo = *reinterpret_cast<const bf16x8*>(wt_lo + woff);
      acc[cf] = __builtin_amdgcn_mfma_f32_16x16x32_bf16(ahi, bhi, acc[cf], 0, 0, 0);
      acc[cf] = __builtin_amdgcn_mfma_f32_16x16x32_bf16(alo, bhi, acc[cf], 0, 0, 0);
      acc[cf] = __builtin_amdgcn_mfma_f32_16x16x32_bf16(ahi, blo, acc[cf], 0, 0, 0);
    }
  }
  __syncthreads();
#pragma unroll
  for (int cf = 0; cf < 2; ++cf) {
    int col = wcol * 32 + cf * 16 + ln;
    float tb = tanh_b[head * NHD + col];
#pragma unroll
    for (int j = 0; j < 4; ++j) {
      int r = wrow * 16 + kg * 4 + j;
      float g = gbuf[r], p = pbuf[r];
      float s = g * acc1[cf][j] + acc2[cf][j] + tb;
      float cand = tanhf(s);
      float hv = bf2f((unsigned short)Ahi[r][col]) + bf2f((unsigned short)Alo[r][col]);
      float nh = hv + p * (cand - hv);
      out_nh[((rowbase + r) * H8 + head) * NHD + col] = nh;
      NHL[r][col] = (short)f2bf(nh);
    }
  }
  __syncthreads();
  floatx4 acc3[4] = {{0.f, 0.f, 0.f, 0.f}, {0.f, 0.f, 0.f, 0.f},
                     {0.f, 0.f, 0.f, 0.f}, {0.f, 0.f, 0.f, 0.f}};
  const size_t wobase = (size_t)head * (16 * ND * 8);
#pragma unroll
  for (int ks = 0; ks < 4; ++ks) {
    bf16x8 a = *reinterpret_cast<const bf16x8*>(&NHL[arow][ks * 32 + kg * 8]);
#pragma unroll
    for (int cf = 0; cf < 4; ++cf) {
      int n0 = wcol * 64 + cf * 16;
      size_t woff = wobase + (size_t)(ks * 4 + kg) * (ND * 8) + (size_t)(n0 + ln) * 8;
      bf16x8 b = *reinterpret_cast<const bf16x8*>(wo + woff);
      acc3[cf] = __builtin_amdgcn_mfma_f32_16x16x32_bf16(a, b, acc3[cf], 0, 0, 0);
    }
  }
#pragma unroll
  for (int cf = 0; cf < 4; ++cf) {
    int col = wcol * 64 + cf * 16 + ln;
    float ob = out_b[head * ND + col];
#pragma unroll
    for (int j = 0; j < 4; ++j) {
      int r = wrow * 16 + kg * 4 + j;
      out[((rowbase + r) * H8 + head) * ND + col] = acc3[cf][j] + ob;
    }
  }
}

extern "C" void kernel_launch(void* const* d_in, const int* in_sizes, int n_in,
                              void* d_out, int out_size, void* d_ws, size_t ws_size,
                              hipStream_t stream) {
  (void)in_sizes; (void)n_in; (void)out_size;
  const float* x      = (const float*)d_in[0];
  const float* h      = (const float*)d_in[1];
  const float* sig_w  = (const float*)d_in[2];
  const float* sig_b  = (const float*)d_in[3];
  const float* tanh_w = (const float*)d_in[4];
  const float* tanh_b = (const float*)d_in[5];
  const float* out_w  = (const float*)d_in[6];
  const float* out_b  = (const float*)d_in[7];

  float* out = (float*)d_out;
  float* out_nh = out + (size_t)NB * H8 * ND;

  if (ws_size >= WS_NEED3) {
    short* wtp_hi = (short*)d_ws;
    short* wtp_lo = wtp_hi + WTP;
    short* wsp_hi = wtp_lo + WTP;
    short* wsp_lo = wsp_hi + WSP;
    short* wop    = wsp_lo + WSP;
    short* xfh    = wop + WOP;
    short* xfl    = xfh + XFP;
    hipLaunchKernelGGL(prep3, dim3(1024), dim3(256), 0, stream,
                       tanh_w, sig_w, out_w, x,
                       wtp_hi, wtp_lo, wsp_hi, wsp_lo, wop, xfh, xfl);
    hipLaunchKernelGGL(gru3, dim3((NB / BM3) * H8), dim3(512), 0, stream,
                       h, sig_b, tanh_b, out_b,
                       wtp_hi, wtp_lo, wsp_hi, wsp_lo, wop, xfh, xfl,
                       out, out_nh);
  } else {
    short* wt_hi = (short*)d_ws;
    short* wt_lo = wt_hi + WT_ELEMS;
    short* wo    = wt_lo + WT_ELEMS;
    hipLaunchKernelGGL(prep_kernel, dim3(512), dim3(256), 0, stream,
                       tanh_w, out_w, wt_hi, wt_lo, wo);
    hipLaunchKernelGGL(gru_main, dim3((NB / BM) * H8), dim3(NT), 0, stream,
                       x, h, sig_w, sig_b, tanh_b, out_b, wt_hi, wt_lo, wo,
                       out, out_nh);
  }
}

// Round 4
// 145.075 us; speedup vs baseline: 1.6001x; 1.0060x over previous
//
#include <hip/hip_runtime.h>
#include <math.h>

typedef short bf16x8 __attribute__((ext_vector_type(8)));
typedef short bf16x4 __attribute__((ext_vector_type(4)));
typedef float floatx4 __attribute__((ext_vector_type(4)));
typedef float floatx2 __attribute__((ext_vector_type(2)));
typedef float floatx16 __attribute__((ext_vector_type(16)));

#define NB   16384
#define H8   8
#define ND   256
#define NHD  128
#define NK   384

__device__ __forceinline__ unsigned short f2bf(float f) {
  unsigned int u = __float_as_uint(f);
  u += 0x7FFFu + ((u >> 16) & 1u);
  return (unsigned short)(u >> 16);
}
__device__ __forceinline__ float bf2f(unsigned short s) {
  return __uint_as_float(((unsigned int)s) << 16);
}
__device__ __forceinline__ float fast_sigmoid(float z) {
  z = fminf(fmaxf(z, -60.f), 60.f);
  return __builtin_amdgcn_rcpf(1.f + __expf(-z));
}
__device__ __forceinline__ float fast_tanh(float s) {
  s = fminf(fmaxf(s, -9.f), 9.f);
  float e = __expf(2.f * s);
  return (e - 1.f) * __builtin_amdgcn_rcpf(e + 1.f);
}

// ================= fragment-packed path (32x32x16) =================
#define WTP (H8 * 24 * 4 * 512)   // tanh_w frags (hi and lo)
#define WSP (H8 * 24 * 512)       // sig_w frags (cols 0,1 real)
#define WOP (H8 * 8 * 8 * 512)    // out_w frags
#define XFP (NB * ND)             // x frags (hi and lo)
#define WS_NEED3 ((size_t)(2 * WTP + 2 * WSP + WOP + 2 * XFP) * 2)

__global__ void prep3(const float* __restrict__ tanh_w,
                      const float* __restrict__ sig_w,
                      const float* __restrict__ out_w,
                      const float* __restrict__ x,
                      short* __restrict__ wtp_hi, short* __restrict__ wtp_lo,
                      short* __restrict__ wsp_hi, short* __restrict__ wsp_lo,
                      short* __restrict__ wop,
                      short* __restrict__ xfh, short* __restrict__ xfl) {
  const int T1 = WTP, T2 = T1 + WSP, T3 = T2 + WOP, T4 = T3 + XFP;
  for (int i = blockIdx.x * blockDim.x + threadIdx.x; i < T4;
       i += gridDim.x * blockDim.x) {
    if (i < T1) {
      int j = i & 7, l = (i >> 3) & 63, ct = (i >> 9) & 3;
      int q2 = i >> 11;
      int ks = q2 % 24, head = q2 / 24;
      int k = ks * 16 + (l >> 5) * 8 + j, n = ct * 32 + (l & 31);
      float w = tanh_w[((size_t)head * NK + k) * NHD + n];
      unsigned short hi = f2bf(w);
      wtp_hi[i] = (short)hi;
      wtp_lo[i] = (short)f2bf(w - bf2f(hi));
    } else if (i < T2) {
      int i2 = i - T1;
      int j = i2 & 7, l = (i2 >> 3) & 63;
      int q = i2 >> 9;
      int ks = q % 24, head = q / 24;
      int k = ks * 16 + (l >> 5) * 8 + j, n = l & 31;
      float w = (n < 2) ? sig_w[((size_t)head * NK + k) * 2 + n] : 0.f;
      unsigned short hi = f2bf(w);
      wsp_hi[i2] = (short)hi;
      wsp_lo[i2] = (short)f2bf(w - bf2f(hi));
    } else if (i < T3) {
      int i3 = i - T2;
      int j = i3 & 7, l = (i3 >> 3) & 63;
      int q = i3 >> 9;
      int ct = q & 7, q2 = q >> 3;
      int ks = q2 & 7, head = q2 >> 3;
      int k = ks * 16 + (l >> 5) * 8 + j, n = ct * 32 + (l & 31);
      wop[i3] = (short)f2bf(out_w[((size_t)head * NHD + k) * ND + n]);
    } else {
      int i4 = i - T3;
      int b = i4 >> 8, c = i4 & 255;
      float v = x[i4];
      int dst = ((b >> 5) * 16 + (c >> 4)) * 512 +
                (((c >> 3) & 1) * 32 + (b & 31)) * 8 + (c & 7);
      unsigned short hi = f2bf(v);
      xfh[dst] = (short)hi;
      xfl[dst] = (short)f2bf(v - bf2f(hi));
    }
  }
}

#define BM3 64

__global__ __launch_bounds__(512, 6) void gru3(
    const float* __restrict__ h, const float* __restrict__ sig_b,
    const float* __restrict__ tanh_b, const float* __restrict__ out_b,
    const short* __restrict__ wtp_hi, const short* __restrict__ wtp_lo,
    const short* __restrict__ wsp_hi, const short* __restrict__ wsp_lo,
    const short* __restrict__ wop,
    const short* __restrict__ xfh, const short* __restrict__ xfl,
    float* __restrict__ out, float* __restrict__ out_nh) {
  __shared__ __align__(16) short AhH[2 * 8 * 512];   // 16 KB h-hi frags; becomes new_h frags
  __shared__ __align__(16) short AhL[2 * 8 * 512];   // 16 KB h-lo frags
  __shared__ float sig_part[2 * 4 * 2 * 32];         // 2 KB [rg][cq][col][row]
  __shared__ float gbuf[BM3], pbuf[BM3];

  const int t = threadIdx.x;
  const int lane = t & 63;
  const int wid = t >> 6;
  const int rg = wid >> 2;        // 0..1 row-group of 32
  const int cq = wid & 3;         // 0..3 col-quad of 32
  const int l31 = lane & 31;
  const int lh = lane >> 5;       // 0/1
  const int head = blockIdx.x & 7;
  const long rowbase = (long)(blockIdx.x >> 3) * BM3;
  const int grg = (int)(blockIdx.x >> 3) * 2;

  // ---- stage h into frag-layout LDS (hi/lo) ----
#pragma unroll
  for (int it = 0; it < 2; ++it) {
    int cidx = it * 512 + t;
    int srg = cidx >> 9, sks = (cidx >> 6) & 7, sl = cidx & 63;
    int r = srg * 32 + (sl & 31);
    int k = sks * 16 + (sl >> 5) * 8;
    const float* hp = h + ((rowbase + r) * H8 + head) * NHD + k;
    floatx4 v0 = *reinterpret_cast<const floatx4*>(hp);
    floatx4 v1 = *reinterpret_cast<const floatx4*>(hp + 4);
    bf16x8 hi8, lo8;
#pragma unroll
    for (int j = 0; j < 4; ++j) {
      unsigned short hb = f2bf(v0[j]);
      hi8[j] = (short)hb; lo8[j] = (short)f2bf(v0[j] - bf2f(hb));
      unsigned short hb2 = f2bf(v1[j]);
      hi8[4 + j] = (short)hb2; lo8[4 + j] = (short)f2bf(v1[j] - bf2f(hb2));
    }
    *reinterpret_cast<bf16x8*>(&AhH[cidx * 8]) = hi8;
    *reinterpret_cast<bf16x8*>(&AhL[cidx * 8]) = lo8;
  }
  __syncthreads();

  // ---- sigmoid pre-pass (accS lives only here; 16 AGPRs freed after) ----
  {
    floatx16 accS;
#pragma unroll
    for (int z = 0; z < 16; ++z) accS[z] = 0.f;
#pragma unroll
    for (int i = 0; i < 6; ++i) {
      int ks = cq * 6 + i;
      bf16x8 ah, al;
      if (ks < 8) {
        ah = *reinterpret_cast<const bf16x8*>(&AhH[((rg * 8 + ks) * 64 + lane) * 8]);
        al = *reinterpret_cast<const bf16x8*>(&AhL[((rg * 8 + ks) * 64 + lane) * 8]);
      } else {
        size_t aoff = ((size_t)((grg + rg) * 16 + (ks - 8)) * 64 + lane) * 8;
        ah = *reinterpret_cast<const bf16x8*>(xfh + aoff);
        al = *reinterpret_cast<const bf16x8*>(xfl + aoff);
      }
      size_t soff = ((size_t)(head * 24 + ks) * 64 + lane) * 8;
      bf16x8 sh = *reinterpret_cast<const bf16x8*>(wsp_hi + soff);
      bf16x8 sl2 = *reinterpret_cast<const bf16x8*>(wsp_lo + soff);
      accS = __builtin_amdgcn_mfma_f32_32x32x16_bf16(ah, sh, accS, 0, 0, 0);
      accS = __builtin_amdgcn_mfma_f32_32x32x16_bf16(al, sh, accS, 0, 0, 0);
      accS = __builtin_amdgcn_mfma_f32_32x32x16_bf16(ah, sl2, accS, 0, 0, 0);
    }
    if (l31 < 2) {
#pragma unroll
      for (int reg = 0; reg < 16; ++reg) {
        int row = (reg & 3) + 8 * (reg >> 2) + 4 * lh;
        sig_part[((rg * 4 + cq) * 2 + l31) * 32 + row] = accS[reg];
      }
    }
  }
  __syncthreads();
  if (t < 128) {
    int r = t >> 1, colc = t & 1;
    int rg2 = r >> 5, rr = r & 31;
    float z = sig_part[((rg2 * 4 + 0) * 2 + colc) * 32 + rr] +
              sig_part[((rg2 * 4 + 1) * 2 + colc) * 32 + rr] +
              sig_part[((rg2 * 4 + 2) * 2 + colc) * 32 + rr] +
              sig_part[((rg2 * 4 + 3) * 2 + colc) * 32 + rr] +
              sig_b[head * 2 + colc];
    float s = fast_sigmoid(z);
    if (colc == 0) gbuf[r] = s; else pbuf[r] = s;
  }
  __syncthreads();

  // ---- tanh matmul: acc1 = h-part, acc2 = x-part (only 32 AGPRs live) ----
  floatx16 acc1, acc2;
#pragma unroll
  for (int z = 0; z < 16; ++z) { acc1[z] = 0.f; acc2[z] = 0.f; }

#pragma unroll
  for (int ks = 0; ks < 8; ++ks) {
    bf16x8 ah = *reinterpret_cast<const bf16x8*>(&AhH[((rg * 8 + ks) * 64 + lane) * 8]);
    bf16x8 al = *reinterpret_cast<const bf16x8*>(&AhL[((rg * 8 + ks) * 64 + lane) * 8]);
    size_t boff = (((size_t)(head * 24 + ks) * 4 + cq) * 64 + lane) * 8;
    bf16x8 bh = *reinterpret_cast<const bf16x8*>(wtp_hi + boff);
    bf16x8 bl = *reinterpret_cast<const bf16x8*>(wtp_lo + boff);
    acc1 = __builtin_amdgcn_mfma_f32_32x32x16_bf16(ah, bh, acc1, 0, 0, 0);
    ac1:
    acc1 = __builtin_amdgcn_mfma_f32_32x32x16_bf16(al, bh, acc1, 0, 0, 0);
    acc1 = __builtin_amdgcn_mfma_f32_32x32x16_bf16(ah, bl, acc1, 0, 0, 0);
  }
#pragma unroll
  for (int xks = 0; xks < 16; ++xks) {
    int ks = 8 + xks;
    size_t aoff = ((size_t)((grg + rg) * 16 + xks) * 64 + lane) * 8;
    bf16x8 ah = *reinterpret_cast<const bf16x8*>(xfh + aoff);
    bf16x8 al = *reinterpret_cast<const bf16x8*>(xfl + aoff);
    size_t boff = (((size_t)(head * 24 + ks) * 4 + cq) * 64 + lane) * 8;
    bf16x8 bh = *reinterpret_cast<const bf16x8*>(wtp_hi + boff);
    bf16x8 bl = *reinterpret_cast<const bf16x8*>(wtp_lo + boff);
    acc2 = __builtin_amdgcn_mfma_f32_32x32x16_bf16(ah, bh, acc2, 0, 0, 0);
    acc2 = __builtin_amdgcn_mfma_f32_32x32x16_bf16(al, bh, acc2, 0, 0, 0);
    acc2 = __builtin_amdgcn_mfma_f32_32x32x16_bf16(ah, bl, acc2, 0, 0, 0);
  }

  __syncthreads();   // all A-frag LDS reads done before new_h overwrites AhH

  // ---- GRU epilogue (writes new_h frags into AhH in place) ----
  const int col = cq * 32 + l31;
  const float tb = tanh_b[head * NHD + col];
#pragma unroll
  for (int reg = 0; reg < 16; ++reg) {
    int rr32 = (reg & 3) + 8 * (reg >> 2) + 4 * lh;
    int r = rg * 32 + rr32;
    float g = gbuf[r], p = pbuf[r];
    float s = g * acc1[reg] + acc2[reg] + tb;
    float cand = fast_tanh(s);
    int el = ((rg * 8 + (col >> 4)) * 64 + ((l31 >> 3) & 1) * 32 + rr32) * 8 + (col & 7);
    float hv = bf2f((unsigned short)AhH[el]) + bf2f((unsigned short)AhL[el]);
    float nh = hv + p * (cand - hv);
    out_nh[((rowbase + r) * H8 + head) * NHD + col] = nh;
    AhH[el] = (short)f2bf(nh);
  }
  __syncthreads();

  // ---- out matmul: new_h (in AhH) @ out_w ----
  floatx16 acc3a, acc3b;
#pragma unroll
  for (int z = 0; z < 16; ++z) { acc3a[z] = 0.f; acc3b[z] = 0.f; }
#pragma unroll
  for (int ks = 0; ks < 8; ++ks) {
    bf16x8 a = *reinterpret_cast<const bf16x8*>(&AhH[((rg * 8 + ks) * 64 + lane) * 8]);
    size_t b0 = (((size_t)(head * 8 + ks) * 8 + cq * 2) * 64 + lane) * 8;
    bf16x8 w0 = *reinterpret_cast<const bf16x8*>(wop + b0);
    bf16x8 w1 = *reinterpret_cast<const bf16x8*>(wop + b0 + 512);
    acc3a = __builtin_amdgcn_mfma_f32_32x32x16_bf16(a, w0, acc3a, 0, 0, 0);
    acc3b = __builtin_amdgcn_mfma_f32_32x32x16_bf16(a, w1, acc3b, 0, 0, 0);
  }
  const float ob0 = out_b[head * ND + cq * 64 + l31];
  const float ob1 = out_b[head * ND + cq * 64 + 32 + l31];
#pragma unroll
  for (int reg = 0; reg < 16; ++reg) {
    int r = rg * 32 + (reg & 3) + 8 * (reg >> 2) + 4 * lh;
    long obase = ((rowbase + r) * H8 + head) * ND;
    out[obase + cq * 64 + l31] = acc3a[reg] + ob0;
    out[obase + cq * 64 + 32 + l31] = acc3b[reg] + ob1;
  }
}

// ================= fallback path (round-2 kernels) =================
#define WT_ELEMS (H8 * NK * NHD)
#define WO_ELEMS (H8 * NHD * ND)

__global__ void prep_kernel(const float* __restrict__ tanh_w,
                            const float* __restrict__ out_w,
                            short* __restrict__ wt_hi,
                            short* __restrict__ wt_lo,
                            short* __restrict__ wo) {
  const int total1 = WT_ELEMS;
  const int total2 = WO_ELEMS;
  for (int i = blockIdx.x * blockDim.x + threadIdx.x; i < total1 + total2;
       i += gridDim.x * blockDim.x) {
    if (i < total1) {
      int hh = i / (NK * NHD);
      int rem = i - hh * NK * NHD;
      int k = rem / NHD, n = rem - k * NHD;
      float w = tanh_w[i];
      unsigned short hi = f2bf(w);
      unsigned short lo = f2bf(w - bf2f(hi));
      int dst = hh * (48 * NHD * 8) + (k >> 3) * (NHD * 8) + n * 8 + (k & 7);
      wt_hi[dst] = (short)hi;
      wt_lo[dst] = (short)lo;
    } else {
      int j = i - total1;
      int hh = j / (NHD * ND);
      int rem = j - hh * NHD * ND;
      int k = rem / ND, n = rem - k * ND;
      int dst = hh * (16 * ND * 8) + (k >> 3) * (ND * 8) + n * 8 + (k & 7);
      wo[dst] = (short)f2bf(out_w[j]);
    }
  }
}

#define BM   32
#define NT   512
#define LDA 392
#define LDNH 136

__global__ __launch_bounds__(NT, 4) void gru_main(
    const float* __restrict__ x, const float* __restrict__ h,
    const float* __restrict__ sig_w, const float* __restrict__ sig_b,
    const float* __restrict__ tanh_b, const float* __restrict__ out_b,
    const short* __restrict__ wt_hi, const short* __restrict__ wt_lo,
    const short* __restrict__ wo,
    float* __restrict__ out, float* __restrict__ out_nh) {
  __shared__ __align__(16) short Ahi[BM][LDA];
  __shared__ __align__(16) short Alo[BM][LDA];
  __shared__ __align__(16) short NHL[BM][LDNH];
  __shared__ floatx2 swl[NK];
  __shared__ float gbuf[BM], pbuf[BM];

  const int t = threadIdx.x;
  const int lane = t & 63;
  const int wid = t >> 6;
  const int wrow = wid >> 2;
  const int wcol = wid & 3;
  const int ln = lane & 15;
  const int kg = lane >> 4;
  const int head = blockIdx.x & 7;
  const long rowbase = (long)(blockIdx.x >> 3) * BM;
  const int arow = wrow * 16 + ln;

#pragma unroll
  for (int i = 0; i < 4; ++i) {
    int idx = i * NT + t;
    int r = idx >> 6, c4 = idx & 63;
    floatx4 v = *reinterpret_cast<const floatx4*>(x + (rowbase + r) * ND + c4 * 4);
    bf16x4 hi, lo;
#pragma unroll
    for (int j = 0; j < 4; ++j) {
      unsigned short hb = f2bf(v[j]);
      hi[j] = (short)hb;
      lo[j] = (short)f2bf(v[j] - bf2f(hb));
    }
    *reinterpret_cast<bf16x4*>(&Ahi[r][NHD + c4 * 4]) = hi;
    *reinterpret_cast<bf16x4*>(&Alo[r][NHD + c4 * 4]) = lo;
  }
#pragma unroll
  for (int i = 0; i < 2; ++i) {
    int idx = i * NT + t;
    int r = idx >> 5, c4 = idx & 31;
    floatx4 v = *reinterpret_cast<const floatx4*>(
        h + ((rowbase + r) * H8 + head) * NHD + c4 * 4);
    bf16x4 hi, lo;
#pragma unroll
    for (int j = 0; j < 4; ++j) {
      unsigned short hb = f2bf(v[j]);
      hi[j] = (short)hb;
      lo[j] = (short)f2bf(v[j] - bf2f(hb));
    }
    *reinterpret_cast<bf16x4*>(&Ahi[r][c4 * 4]) = hi;
    *reinterpret_cast<bf16x4*>(&Alo[r][c4 * 4]) = lo;
  }
  if (t < NK)
    swl[t] = *reinterpret_cast<const floatx2*>(sig_w + ((size_t)head * NK + t) * 2);
  __syncthreads();
  {
    int r = t >> 4, u = t & 15;
    float a0 = 0.f, a1 = 0.f;
#pragma unroll
    for (int kk = 0; kk < 24; ++kk) {
      int k = u + kk * 16;
      float a = bf2f((unsigned short)Ahi[r][k]) + bf2f((unsigned short)Alo[r][k]);
      floatx2 w = swl[k];
      a0 += a * w[0];
      a1 += a * w[1];
    }
#pragma unroll
    for (int off = 1; off < 16; off <<= 1) {
      a0 += __shfl_xor(a0, off);
      a1 += __shfl_xor(a1, off);
    }
    if (u == 0) {
      gbuf[r] = fast_sigmoid(a0 + sig_b[head * 2 + 0]);
      pbuf[r] = fast_sigmoid(a1 + sig_b[head * 2 + 1]);
    }
  }
  floatx4 acc1[2] = {{0.f, 0.f, 0.f, 0.f}, {0.f, 0.f, 0.f, 0.f}};
  floatx4 acc2[2] = {{0.f, 0.f, 0.f, 0.f}, {0.f, 0.f, 0.f, 0.f}};
  const size_t wtbase = (size_t)head * (48 * NHD * 8);
#pragma unroll
  for (int ks = 0; ks < 12; ++ks) {
    bf16x8 ahi = *reinterpret_cast<const bf16x8*>(&Ahi[arow][ks * 32 + kg * 8]);
    bf16x8 alo = *reinterpret_cast<const bf16x8*>(&Alo[arow][ks * 32 + kg * 8]);
    floatx4* acc = (ks < 4) ? acc1 : acc2;
#pragma unroll
    for (int cf = 0; cf < 2; ++cf) {
      int n0 = wcol * 32 + cf * 16;
      size_t woff = wtbase + (size_t)(ks * 4 + kg) * (NHD * 8) + (size_t)(n0 + ln) * 8;
      bf16x8 bhi = *reinterpret_cast<const bf16x8*>(wt_hi + woff);
      bf16x8 blo = *reinterpret_cast<const bf16x8*>(wt_lo + woff);
      acc[cf] = __builtin_amdgcn_mfma_f32_16x16x32_bf16(ahi, bhi, acc[cf], 0, 0, 0);
      acc[cf] = __builtin_amdgcn_mfma_f32_16x16x32_bf16(alo, bhi, acc[cf], 0, 0, 0);
      acc[cf] = __builtin_amdgcn_mfma_f32_16x16x32_bf16(ahi, blo, acc[cf], 0, 0, 0);
    }
  }
  __syncthreads();
#pragma unroll
  for (int cf = 0; cf < 2; ++cf) {
    int col = wcol * 32 + cf * 16 + ln;
    float tb = tanh_b[head * NHD + col];
#pragma unroll
    for (int j = 0; j < 4; ++j) {
      int r = wrow * 16 + kg * 4 + j;
      float g = gbuf[r], p = pbuf[r];
      float s = g * acc1[cf][j] + acc2[cf][j] + tb;
      float cand = fast_tanh(s);
      float hv = bf2f((unsigned short)Ahi[r][col]) + bf2f((unsigned short)Alo[r][col]);
      float nh = hv + p * (cand - hv);
      out_nh[((rowbase + r) * H8 + head) * NHD + col] = nh;
      NHL[r][col] = (short)f2bf(nh);
    }
  }
  __syncthreads();
  floatx4 acc3[4] = {{0.f, 0.f, 0.f, 0.f}, {0.f, 0.f, 0.f, 0.f},
                     {0.f, 0.f, 0.f, 0.f}, {0.f, 0.f, 0.f, 0.f}};
  const size_t wobase = (size_t)head * (16 * ND * 8);
#pragma unroll
  for (int ks = 0; ks < 4; ++ks) {
    bf16x8 a = *reinterpret_cast<const bf16x8*>(&NHL[arow][ks * 32 + kg * 8]);
#pragma unroll
    for (int cf = 0; cf < 4; ++cf) {
      int n0 = wcol * 64 + cf * 16;
      size_t woff = wobase + (size_t)(ks * 4 + kg) * (ND * 8) + (size_t)(n0 + ln) * 8;
      bf16x8 b = *reinterpret_cast<const bf16x8*>(wo + woff);
      acc3[cf] = __builtin_amdgcn_mfma_f32_16x16x32_bf16(a, b, acc3[cf], 0, 0, 0);
    }
  }
#pragma unroll
  for (int cf = 0; cf < 4; ++cf) {
    int col = wcol * 64 + cf * 16 + ln;
    float ob = out_b[head * ND + col];
#pragma unroll
    for (int j = 0; j < 4; ++j) {
      int r = wrow * 16 + kg * 4 + j;
      out[((rowbase + r) * H8 + head) * ND + col] = acc3[cf][j] + ob;
    }
  }
}

extern "C" void kernel_launch(void* const* d_in, const int* in_sizes, int n_in,
                              void* d_out, int out_size, void* d_ws, size_t ws_size,
                              hipStream_t stream) {
  (void)in_sizes; (void)n_in; (void)out_size;
  const float* x      = (const float*)d_in[0];
  const float* h      = (const float*)d_in[1];
  const float* sig_w  = (const float*)d_in[2];
  const float* sig_b  = (const float*)d_in[3];
  const float* tanh_w = (const float*)d_in[4];
  const float* tanh_b = (const float*)d_in[5];
  const float* out_w  = (const float*)d_in[6];
  const float* out_b  = (const float*)d_in[7];

  float* out = (float*)d_out;
  float* out_nh = out + (size_t)NB * H8 * ND;

  if (ws_size >= WS_NEED3) {
    short* wtp_hi = (short*)d_ws;
    short* wtp_lo = wtp_hi + WTP;
    short* wsp_hi = wtp_lo + WTP;
    short* wsp_lo = wsp_hi + WSP;
    short* wop    = wsp_lo + WSP;
    short* xfh    = wop + WOP;
    short* xfl    = xfh + XFP;
    hipLaunchKernelGGL(prep3, dim3(2048), dim3(256), 0, stream,
                       tanh_w, sig_w, out_w, x,
                       wtp_hi, wtp_lo, wsp_hi, wsp_lo, wop, xfh, xfl);
    hipLaunchKernelGGL(gru3, dim3((NB / BM3) * H8), dim3(512), 0, stream,
                       h, sig_b, tanh_b, out_b,
                       wtp_hi, wtp_lo, wsp_hi, wsp_lo, wop, xfh, xfl,
                       out, out_nh);
  } else {
    short* wt_hi = (short*)d_ws;
    short* wt_lo = wt_hi + WT_ELEMS;
    short* wo    = wt_lo + WT_ELEMS;
    hipLaunchKernelGGL(prep_kernel, dim3(512), dim3(256), 0, stream,
                       tanh_w, out_w, wt_hi, wt_lo, wo);
    hipLaunchKernelGGL(gru_main, dim3((NB / BM) * H8), dim3(NT), 0, stream,
                       x, h, sig_w, sig_b, tanh_b, out_b, wt_hi, wt_lo, wo,
                       out, out_nh);
  }
}

// Round 5
// 142.032 us; speedup vs baseline: 1.6344x; 1.0214x over previous
//
#include <hip/hip_runtime.h>
#include <math.h>

typedef short bf16x8 __attribute__((ext_vector_type(8)));
typedef short bf16x4 __attribute__((ext_vector_type(4)));
typedef float floatx4 __attribute__((ext_vector_type(4)));
typedef float floatx2 __attribute__((ext_vector_type(2)));
typedef float floatx16 __attribute__((ext_vector_type(16)));

#define NB   16384
#define H8   8
#define ND   256
#define NHD  128
#define NK   384

__device__ __forceinline__ unsigned short f2bf(float f) {
  unsigned int u = __float_as_uint(f);
  u += 0x7FFFu + ((u >> 16) & 1u);
  return (unsigned short)(u >> 16);
}
__device__ __forceinline__ float bf2f(unsigned short s) {
  return __uint_as_float(((unsigned int)s) << 16);
}
__device__ __forceinline__ float fast_sigmoid(float z) {
  z = fminf(fmaxf(z, -60.f), 60.f);
  return __builtin_amdgcn_rcpf(1.f + __expf(-z));
}
__device__ __forceinline__ float fast_tanh(float s) {
  s = fminf(fmaxf(s, -9.f), 9.f);
  float e = __expf(2.f * s);
  return (e - 1.f) * __builtin_amdgcn_rcpf(e + 1.f);
}

// ================= fragment-packed path (32x32x16) =================
#define WTP (H8 * 24 * 4 * 512)   // tanh_w frags (hi and lo)
#define WSP (H8 * 24 * 512)       // sig_w frags (cols 0,1 real)
#define WOP (H8 * 8 * 8 * 512)    // out_w frags
#define XFP (NB * ND)             // x frags (hi and lo)
#define WS_NEED3 ((size_t)(2 * WTP + 2 * WSP + WOP + 2 * XFP) * 2)

// One launch, three roles:
//  blocks 0..191   : tanh_w slab transpose (head, ks) via LDS, coalesced R+W
//  blocks 192..255 : out_w slab transpose (head, ks)
//  blocks 256..    : grid-stride sig_w frags + x frags (coalesced already)
__global__ void prep3b(const float* __restrict__ tanh_w,
                       const float* __restrict__ sig_w,
                       const float* __restrict__ out_w,
                       const float* __restrict__ x,
                       short* __restrict__ wtp_hi, short* __restrict__ wtp_lo,
                       short* __restrict__ wsp_hi, short* __restrict__ wsp_lo,
                       short* __restrict__ wop,
                       short* __restrict__ xfh, short* __restrict__ xfl) {
  __shared__ float tile[16 * 260];
  const int t = threadIdx.x;
  const int b = blockIdx.x;
  if (b < 192) {
    // tanh_w slab: 16 rows x 128 cols, head = b/24, ks = b%24
    int head = b / 24, ks = b % 24;
    const float* slab = tanh_w + ((size_t)head * NK + ks * 16) * NHD;
#pragma unroll
    for (int it = 0; it < 2; ++it) {
      int i = it * 256 + t;                  // 512 float4 total
      floatx4 v = reinterpret_cast<const floatx4*>(slab)[i];
      int r = i >> 5, c4 = i & 31;
      *reinterpret_cast<floatx4*>(&tile[r * 132 + c4 * 4]) = v;
    }
    __syncthreads();
    int ct = t >> 6, l = t & 63;
    bf16x8 hi8, lo8;
#pragma unroll
    for (int j = 0; j < 8; ++j) {
      float w = tile[((l >> 5) * 8 + j) * 132 + ct * 32 + (l & 31)];
      unsigned short hb = f2bf(w);
      hi8[j] = (short)hb;
      lo8[j] = (short)f2bf(w - bf2f(hb));
    }
    size_t dst = ((((size_t)head * 24 + ks) * 4 + ct) * 64 + l) * 8;
    *reinterpret_cast<bf16x8*>(wtp_hi + dst) = hi8;
    *reinterpret_cast<bf16x8*>(wtp_lo + dst) = lo8;
  } else if (b < 256) {
    // out_w slab: 16 rows x 256 cols, head = (b-192)/8, ks = (b-192)%8
    int head = (b - 192) / 8, ks = (b - 192) % 8;
    const float* slab = out_w + ((size_t)head * NHD + ks * 16) * ND;
#pragma unroll
    for (int it = 0; it < 4; ++it) {
      int i = it * 256 + t;                  // 1024 float4 total
      floatx4 v = reinterpret_cast<const floatx4*>(slab)[i];
      int r = i >> 6, c4 = i & 63;
      *reinterpret_cast<floatx4*>(&tile[r * 260 + c4 * 4]) = v;
    }
    __syncthreads();
#pragma unroll
    for (int u = 0; u < 2; ++u) {
      int idx = u * 256 + t;
      int ct = idx >> 6, l = idx & 63;
      bf16x8 o8;
#pragma unroll
      for (int j = 0; j < 8; ++j) {
        float w = tile[((l >> 5) * 8 + j) * 260 + ct * 32 + (l & 31)];
        o8[j] = (short)f2bf(w);
      }
      size_t dst = ((((size_t)head * 8 + ks) * 8 + ct) * 64 + l) * 8;
      *reinterpret_cast<bf16x8*>(wop + dst) = o8;
    }
  } else {
    const int T2 = WSP, T3 = T2 + XFP;
    for (int i = (b - 256) * 256 + t; i < T3; i += (gridDim.x - 256) * 256) {
      if (i < T2) {
        int j = i & 7, l = (i >> 3) & 63;
        int q = i >> 9;
        int ks = q % 24, head = q / 24;
        int k = ks * 16 + (l >> 5) * 8 + j, n = l & 31;
        float w = (n < 2) ? sig_w[((size_t)head * NK + k) * 2 + n] : 0.f;
        unsigned short hi = f2bf(w);
        wsp_hi[i] = (short)hi;
        wsp_lo[i] = (short)f2bf(w - bf2f(hi));
      } else {
        int i4 = i - T2;
        int bb = i4 >> 8, c = i4 & 255;
        float v = x[i4];
        int dst = ((bb >> 5) * 16 + (c >> 4)) * 512 +
                  (((c >> 3) & 1) * 32 + (bb & 31)) * 8 + (c & 7);
        unsigned short hi = f2bf(v);
        xfh[dst] = (short)hi;
        xfl[dst] = (short)f2bf(v - bf2f(hi));
      }
    }
  }
}

#define BM3 64

__global__ __launch_bounds__(512, 4) void gru3(
    const float* __restrict__ h, const float* __restrict__ sig_b,
    const float* __restrict__ tanh_b, const float* __restrict__ out_b,
    const short* __restrict__ wtp_hi, const short* __restrict__ wtp_lo,
    const short* __restrict__ wsp_hi, const short* __restrict__ wsp_lo,
    const short* __restrict__ wop,
    const short* __restrict__ xfh, const short* __restrict__ xfl,
    float* __restrict__ out, float* __restrict__ out_nh) {
  __shared__ __align__(16) short AhH[2 * 8 * 512];   // h-hi frags; becomes new_h frags
  __shared__ __align__(16) short AhL[2 * 8 * 512];   // h-lo frags
  __shared__ float sig_part[2 * 4 * 2 * 32];
  __shared__ float gbuf[BM3], pbuf[BM3];

  const int t = threadIdx.x;
  const int lane = t & 63;
  const int wid = t >> 6;
  const int rg = wid >> 2;        // 0..1 row-group of 32
  const int cq = wid & 3;         // 0..3 col-quad of 32
  const int l31 = lane & 31;
  const int lh = lane >> 5;
  const int head = blockIdx.x & 7;
  const long rowbase = (long)(blockIdx.x >> 3) * BM3;
  const int grg = (int)(blockIdx.x >> 3) * 2;

  // ---- stage h into frag-layout LDS (hi/lo) ----
#pragma unroll
  for (int it = 0; it < 2; ++it) {
    int cidx = it * 512 + t;
    int srg = cidx >> 9, sks = (cidx >> 6) & 7, sl = cidx & 63;
    int r = srg * 32 + (sl & 31);
    int k = sks * 16 + (sl >> 5) * 8;
    const float* hp = h + ((rowbase + r) * H8 + head) * NHD + k;
    floatx4 v0 = *reinterpret_cast<const floatx4*>(hp);
    floatx4 v1 = *reinterpret_cast<const floatx4*>(hp + 4);
    bf16x8 hi8, lo8;
#pragma unroll
    for (int j = 0; j < 4; ++j) {
      unsigned short hb = f2bf(v0[j]);
      hi8[j] = (short)hb; lo8[j] = (short)f2bf(v0[j] - bf2f(hb));
      unsigned short hb2 = f2bf(v1[j]);
      hi8[4 + j] = (short)hb2; lo8[4 + j] = (short)f2bf(v1[j] - bf2f(hb2));
    }
    *reinterpret_cast<bf16x8*>(&AhH[cidx * 8]) = hi8;
    *reinterpret_cast<bf16x8*>(&AhL[cidx * 8]) = lo8;
  }
  __syncthreads();

  // ---- unified K-loop: tanh h-part (acc1), x-part (acc2), sig (accS) ----
  floatx16 acc1, acc2, accS;
#pragma unroll
  for (int z = 0; z < 16; ++z) { acc1[z] = 0.f; acc2[z] = 0.f; accS[z] = 0.f; }

  const short* __restrict__ bh_p = wtp_hi + (((size_t)head * 24 * 4 + cq) * 512) + lane * 8;
  const short* __restrict__ bl_p = wtp_lo + (((size_t)head * 24 * 4 + cq) * 512) + lane * 8;
  const short* __restrict__ sh_p = wsp_hi + ((size_t)head * 24 * 512) + lane * 8;
  const short* __restrict__ sl_p = wsp_lo + ((size_t)head * 24 * 512) + lane * 8;
  const short* __restrict__ xh_p = xfh + ((size_t)(grg + rg) * 16 * 512) + lane * 8;
  const short* __restrict__ xl_p = xfl + ((size_t)(grg + rg) * 16 * 512) + lane * 8;

  bf16x8 bh_n = *reinterpret_cast<const bf16x8*>(bh_p);
  bf16x8 bl_n = *reinterpret_cast<const bf16x8*>(bl_p);
  bf16x8 ah_n, al_n;

#pragma unroll
  for (int ks = 0; ks < 8; ++ks) {
    bf16x8 bh = bh_n, bl = bl_n;
    bh_n = *reinterpret_cast<const bf16x8*>(bh_p + (ks + 1) * 2048);
    bl_n = *reinterpret_cast<const bf16x8*>(bl_p + (ks + 1) * 2048);
    if (ks == 7) {
      ah_n = *reinterpret_cast<const bf16x8*>(xh_p);
      al_n = *reinterpret_cast<const bf16x8*>(xl_p);
    }
    bf16x8 ah = *reinterpret_cast<const bf16x8*>(&AhH[((rg * 8 + ks) * 64 + lane) * 8]);
    bf16x8 al = *reinterpret_cast<const bf16x8*>(&AhL[((rg * 8 + ks) * 64 + lane) * 8]);
    acc1 = __builtin_amdgcn_mfma_f32_32x32x16_bf16(ah, bh, acc1, 0, 0, 0);
    acc1 = __builtin_amdgcn_mfma_f32_32x32x16_bf16(al, bh, acc1, 0, 0, 0);
    acc1 = __builtin_amdgcn_mfma_f32_32x32x16_bf16(ah, bl, acc1, 0, 0, 0);
    if (ks / 6 == cq) {
      bf16x8 sh = *reinterpret_cast<const bf16x8*>(sh_p + ks * 512);
      bf16x8 sl2 = *reinterpret_cast<const bf16x8*>(sl_p + ks * 512);
      accS = __builtin_amdgcn_mfma_f32_32x32x16_bf16(ah, sh, accS, 0, 0, 0);
      accS = __builtin_amdgcn_mfma_f32_32x32x16_bf16(al, sh, accS, 0, 0, 0);
      accS = __builtin_amdgcn_mfma_f32_32x32x16_bf16(ah, sl2, accS, 0, 0, 0);
    }
  }
#pragma unroll
  for (int xks = 0; xks < 16; ++xks) {
    const int ks = 8 + xks;
    bf16x8 ah = ah_n, al = al_n;
    if (xks < 15) {
      ah_n = *reinterpret_cast<const bf16x8*>(xh_p + (xks + 1) * 512);
      al_n = *reinterpret_cast<const bf16x8*>(xl_p + (xks + 1) * 512);
    }
    bf16x8 bh = bh_n, bl = bl_n;
    if (ks < 23) {
      bh_n = *reinterpret_cast<const bf16x8*>(bh_p + (ks + 1) * 2048);
      bl_n = *reinterpret_cast<const bf16x8*>(bl_p + (ks + 1) * 2048);
    }
    acc2 = __builtin_amdgcn_mfma_f32_32x32x16_bf16(ah, bh, acc2, 0, 0, 0);
    acc2 = __builtin_amdgcn_mfma_f32_32x32x16_bf16(al, bh, acc2, 0, 0, 0);
    acc2 = __builtin_amdgcn_mfma_f32_32x32x16_bf16(ah, bl, acc2, 0, 0, 0);
    if (ks / 6 == cq) {
      bf16x8 sh = *reinterpret_cast<const bf16x8*>(sh_p + ks * 512);
      bf16x8 sl2 = *reinterpret_cast<const bf16x8*>(sl_p + ks * 512);
      accS = __builtin_amdgcn_mfma_f32_32x32x16_bf16(ah, sh, accS, 0, 0, 0);
      accS = __builtin_amdgcn_mfma_f32_32x32x16_bf16(al, sh, accS, 0, 0, 0);
      accS = __builtin_amdgcn_mfma_f32_32x32x16_bf16(ah, sl2, accS, 0, 0, 0);
    }
  }

  // ---- sig partials -> reduce -> gates ----
  if (l31 < 2) {
#pragma unroll
    for (int reg = 0; reg < 16; ++reg) {
      int row = (reg & 3) + 8 * (reg >> 2) + 4 * lh;
      sig_part[((rg * 4 + cq) * 2 + l31) * 32 + row] = accS[reg];
    }
  }
  __syncthreads();
  if (t < 128) {
    int r = t >> 1, colc = t & 1;
    int rg2 = r >> 5, rr = r & 31;
    float z = sig_part[((rg2 * 4 + 0) * 2 + colc) * 32 + rr] +
              sig_part[((rg2 * 4 + 1) * 2 + colc) * 32 + rr] +
              sig_part[((rg2 * 4 + 2) * 2 + colc) * 32 + rr] +
              sig_part[((rg2 * 4 + 3) * 2 + colc) * 32 + rr] +
              sig_b[head * 2 + colc];
    float s = fast_sigmoid(z);
    if (colc == 0) gbuf[r] = s; else pbuf[r] = s;
  }
  __syncthreads();

  // ---- GRU epilogue (writes new_h frags into AhH in place) ----
  const int col = cq * 32 + l31;
  const float tb = tanh_b[head * NHD + col];
#pragma unroll
  for (int reg = 0; reg < 16; ++reg) {
    int rr32 = (reg & 3) + 8 * (reg >> 2) + 4 * lh;
    int r = rg * 32 + rr32;
    float g = gbuf[r], p = pbuf[r];
    float s = g * acc1[reg] + acc2[reg] + tb;
    float cand = fast_tanh(s);
    int el = ((rg * 8 + (col >> 4)) * 64 + ((l31 >> 3) & 1) * 32 + rr32) * 8 + (col & 7);
    float hv = bf2f((unsigned short)AhH[el]) + bf2f((unsigned short)AhL[el]);
    float nh = hv + p * (cand - hv);
    out_nh[((rowbase + r) * H8 + head) * NHD + col] = nh;
    AhH[el] = (short)f2bf(nh);
  }
  __syncthreads();

  // ---- out matmul: new_h (in AhH) @ out_w, 1-deep wop prefetch ----
  floatx16 acc3a, acc3b;
#pragma unroll
  for (int z = 0; z < 16; ++z) { acc3a[z] = 0.f; acc3b[z] = 0.f; }
  const short* __restrict__ wo_p = wop + (((size_t)head * 8 * 8 + cq * 2) * 512) + lane * 8;
  bf16x8 w0n = *reinterpret_cast<const bf16x8*>(wo_p);
  bf16x8 w1n = *reinterpret_cast<const bf16x8*>(wo_p + 512);
#pragma unroll
  for (int ks = 0; ks < 8; ++ks) {
    bf16x8 w0 = w0n, w1 = w1n;
    if (ks < 7) {
      w0n = *reinterpret_cast<const bf16x8*>(wo_p + (ks + 1) * 4096);
      w1n = *reinterpret_cast<const bf16x8*>(wo_p + (ks + 1) * 4096 + 512);
    }
    bf16x8 a = *reinterpret_cast<const bf16x8*>(&AhH[((rg * 8 + ks) * 64 + lane) * 8]);
    acc3a = __builtin_amdgcn_mfma_f32_32x32x16_bf16(a, w0, acc3a, 0, 0, 0);
    acc3b = __builtin_amdgcn_mfma_f32_32x32x16_bf16(a, w1, acc3b, 0, 0, 0);
  }
  const float ob0 = out_b[head * ND + cq * 64 + l31];
  const float ob1 = out_b[head * ND + cq * 64 + 32 + l31];
#pragma unroll
  for (int reg = 0; reg < 16; ++reg) {
    int r = rg * 32 + (reg & 3) + 8 * (reg >> 2) + 4 * lh;
    long obase = ((rowbase + r) * H8 + head) * ND;
    out[obase + cq * 64 + l31] = acc3a[reg] + ob0;
    out[obase + cq * 64 + 32 + l31] = acc3b[reg] + ob1;
  }
}

// ================= fallback path (round-2 kernels) =================
#define WT_ELEMS (H8 * NK * NHD)
#define WO_ELEMS (H8 * NHD * ND)

__global__ void prep_kernel(const float* __restrict__ tanh_w,
                            const float* __restrict__ out_w,
                            short* __restrict__ wt_hi,
                            short* __restrict__ wt_lo,
                            short* __restrict__ wo) {
  const int total1 = WT_ELEMS;
  const int total2 = WO_ELEMS;
  for (int i = blockIdx.x * blockDim.x + threadIdx.x; i < total1 + total2;
       i += gridDim.x * blockDim.x) {
    if (i < total1) {
      int hh = i / (NK * NHD);
      int rem = i - hh * NK * NHD;
      int k = rem / NHD, n = rem - k * NHD;
      float w = tanh_w[i];
      unsigned short hi = f2bf(w);
      unsigned short lo = f2bf(w - bf2f(hi));
      int dst = hh * (48 * NHD * 8) + (k >> 3) * (NHD * 8) + n * 8 + (k & 7);
      wt_hi[dst] = (short)hi;
      wt_lo[dst] = (short)lo;
    } else {
      int j = i - total1;
      int hh = j / (NHD * ND);
      int rem = j - hh * NHD * ND;
      int k = rem / ND, n = rem - k * ND;
      int dst = hh * (16 * ND * 8) + (k >> 3) * (ND * 8) + n * 8 + (k & 7);
      wo[dst] = (short)f2bf(out_w[j]);
    }
  }
}

#define BM   32
#define NT   512
#define LDA 392
#define LDNH 136

__global__ __launch_bounds__(NT, 4) void gru_main(
    const float* __restrict__ x, const float* __restrict__ h,
    const float* __restrict__ sig_w, const float* __restrict__ sig_b,
    const float* __restrict__ tanh_b, const float* __restrict__ out_b,
    const short* __restrict__ wt_hi, const short* __restrict__ wt_lo,
    const short* __restrict__ wo,
    float* __restrict__ out, float* __restrict__ out_nh) {
  __shared__ __align__(16) short Ahi[BM][LDA];
  __shared__ __align__(16) short Alo[BM][LDA];
  __shared__ __align__(16) short NHL[BM][LDNH];
  __shared__ floatx2 swl[NK];
  __shared__ float gbuf[BM], pbuf[BM];

  const int t = threadIdx.x;
  const int lane = t & 63;
  const int wid = t >> 6;
  const int wrow = wid >> 2;
  const int wcol = wid & 3;
  const int ln = lane & 15;
  const int kg = lane >> 4;
  const int head = blockIdx.x & 7;
  const long rowbase = (long)(blockIdx.x >> 3) * BM;
  const int arow = wrow * 16 + ln;

#pragma unroll
  for (int i = 0; i < 4; ++i) {
    int idx = i * NT + t;
    int r = idx >> 6, c4 = idx & 63;
    floatx4 v = *reinterpret_cast<const floatx4*>(x + (rowbase + r) * ND + c4 * 4);
    bf16x4 hi, lo;
#pragma unroll
    for (int j = 0; j < 4; ++j) {
      unsigned short hb = f2bf(v[j]);
      hi[j] = (short)hb;
      lo[j] = (short)f2bf(v[j] - bf2f(hb));
    }
    *reinterpret_cast<bf16x4*>(&Ahi[r][NHD + c4 * 4]) = hi;
    *reinterpret_cast<bf16x4*>(&Alo[r][NHD + c4 * 4]) = lo;
  }
#pragma unroll
  for (int i = 0; i < 2; ++i) {
    int idx = i * NT + t;
    int r = idx >> 5, c4 = idx & 31;
    floatx4 v = *reinterpret_cast<const floatx4*>(
        h + ((rowbase + r) * H8 + head) * NHD + c4 * 4);
    bf16x4 hi, lo;
#pragma unroll
    for (int j = 0; j < 4; ++j) {
      unsigned short hb = f2bf(v[j]);
      hi[j] = (short)hb;
      lo[j] = (short)f2bf(v[j] - bf2f(hb));
    }
    *reinterpret_cast<bf16x4*>(&Ahi[r][c4 * 4]) = hi;
    *reinterpret_cast<bf16x4*>(&Alo[r][c4 * 4]) = lo;
  }
  if (t < NK)
    swl[t] = *reinterpret_cast<const floatx2*>(sig_w + ((size_t)head * NK + t) * 2);
  __syncthreads();
  {
    int r = t >> 4, u = t & 15;
    float a0 = 0.f, a1 = 0.f;
#pragma unroll
    for (int kk = 0; kk < 24; ++kk) {
      int k = u + kk * 16;
      float a = bf2f((unsigned short)Ahi[r][k]) + bf2f((unsigned short)Alo[r][k]);
      floatx2 w = swl[k];
      a0 += a * w[0];
      a1 += a * w[1];
    }
#pragma unroll
    for (int off = 1; off < 16; off <<= 1) {
      a0 += __shfl_xor(a0, off);
      a1 += __shfl_xor(a1, off);
    }
    if (u == 0) {
      gbuf[r] = fast_sigmoid(a0 + sig_b[head * 2 + 0]);
      pbuf[r] = fast_sigmoid(a1 + sig_b[head * 2 + 1]);
    }
  }
  floatx4 acc1[2] = {{0.f, 0.f, 0.f, 0.f}, {0.f, 0.f, 0.f, 0.f}};
  floatx4 acc2[2] = {{0.f, 0.f, 0.f, 0.f}, {0.f, 0.f, 0.f, 0.f}};
  const size_t wtbase = (size_t)head * (48 * NHD * 8);
#pragma unroll
  for (int ks = 0; ks < 12; ++ks) {
    bf16x8 ahi = *reinterpret_cast<const bf16x8*>(&Ahi[arow][ks * 32 + kg * 8]);
    bf16x8 alo = *reinterpret_cast<const bf16x8*>(&Alo[arow][ks * 32 + kg * 8]);
    floatx4* acc = (ks < 4) ? acc1 : acc2;
#pragma unroll
    for (int cf = 0; cf < 2; ++cf) {
      int n0 = wcol * 32 + cf * 16;
      size_t woff = wtbase + (size_t)(ks * 4 + kg) * (NHD * 8) + (size_t)(n0 + ln) * 8;
      bf16x8 bhi = *reinterpret_cast<const bf16x8*>(wt_hi + woff);
      bf16x8 blo = *reinterpret_cast<const bf16x8*>(wt_lo + woff);
      acc[cf] = __builtin_amdgcn_mfma_f32_16x16x32_bf16(ahi, bhi, acc[cf], 0, 0, 0);
      acc[cf] = __builtin_amdgcn_mfma_f32_16x16x32_bf16(alo, bhi, acc[cf], 0, 0, 0);
      acc[cf] = __builtin_amdgcn_mfma_f32_16x16x32_bf16(ahi, blo, acc[cf], 0, 0, 0);
    }
  }
  __syncthreads();
#pragma unroll
  for (int cf = 0; cf < 2; ++cf) {
    int col = wcol * 32 + cf * 16 + ln;
    float tb = tanh_b[head * NHD + col];
#pragma unroll
    for (int j = 0; j < 4; ++j) {
      int r = wrow * 16 + kg * 4 + j;
      float g = gbuf[r], p = pbuf[r];
      float s = g * acc1[cf][j] + acc2[cf][j] + tb;
      float cand = fast_tanh(s);
      float hv = bf2f((unsigned short)Ahi[r][col]) + bf2f((unsigned short)Alo[r][col]);
      float nh = hv + p * (cand - hv);
      out_nh[((rowbase + r) * H8 + head) * NHD + col] = nh;
      NHL[r][col] = (short)f2bf(nh);
    }
  }
  __syncthreads();
  floatx4 acc3[4] = {{0.f, 0.f, 0.f, 0.f}, {0.f, 0.f, 0.f, 0.f},
                     {0.f, 0.f, 0.f, 0.f}, {0.f, 0.f, 0.f, 0.f}};
  const size_t wobase = (size_t)head * (16 * ND * 8);
#pragma unroll
  for (int ks = 0; ks < 4; ++ks) {
    bf16x8 a = *reinterpret_cast<const bf16x8*>(&NHL[arow][ks * 32 + kg * 8]);
#pragma unroll
    for (int cf = 0; cf < 4; ++cf) {
      int n0 = wcol * 64 + cf * 16;
      size_t woff = wobase + (size_t)(ks * 4 + kg) * (ND * 8) + (size_t)(n0 + ln) * 8;
      bf16x8 bfr = *reinterpret_cast<const bf16x8*>(wo + woff);
      acc3[cf] = __builtin_amdgcn_mfma_f32_16x16x32_bf16(a, bfr, acc3[cf], 0, 0, 0);
    }
  }
#pragma unroll
  for (int cf = 0; cf < 4; ++cf) {
    int col = wcol * 64 + cf * 16 + ln;
    float ob = out_b[head * ND + col];
#pragma unroll
    for (int j = 0; j < 4; ++j) {
      int r = wrow * 16 + kg * 4 + j;
      out[((rowbase + r) * H8 + head) * ND + col] = acc3[cf][j] + ob;
    }
  }
}

extern "C" void kernel_launch(void* const* d_in, const int* in_sizes, int n_in,
                              void* d_out, int out_size, void* d_ws, size_t ws_size,
                              hipStream_t stream) {
  (void)in_sizes; (void)n_in; (void)out_size;
  const float* x      = (const float*)d_in[0];
  const float* h      = (const float*)d_in[1];
  const float* sig_w  = (const float*)d_in[2];
  const float* sig_b  = (const float*)d_in[3];
  const float* tanh_w = (const float*)d_in[4];
  const float* tanh_b = (const float*)d_in[5];
  const float* out_w  = (const float*)d_in[6];
  const float* out_b  = (const float*)d_in[7];

  float* out = (float*)d_out;
  float* out_nh = out + (size_t)NB * H8 * ND;

  if (ws_size >= WS_NEED3) {
    short* wtp_hi = (short*)d_ws;
    short* wtp_lo = wtp_hi + WTP;
    short* wsp_hi = wtp_lo + WTP;
    short* wsp_lo = wsp_hi + WSP;
    short* wop    = wsp_lo + WSP;
    short* xfh    = wop + WOP;
    short* xfl    = xfh + XFP;
    hipLaunchKernelGGL(prep3b, dim3(256 + 1024), dim3(256), 0, stream,
                       tanh_w, sig_w, out_w, x,
                       wtp_hi, wtp_lo, wsp_hi, wsp_lo, wop, xfh, xfl);
    hipLaunchKernelGGL(gru3, dim3((NB / BM3) * H8), dim3(512), 0, stream,
                       h, sig_b, tanh_b, out_b,
                       wtp_hi, wtp_lo, wsp_hi, wsp_lo, wop, xfh, xfl,
                       out, out_nh);
  } else {
    short* wt_hi = (short*)d_ws;
    short* wt_lo = wt_hi + WT_ELEMS;
    short* wo    = wt_lo + WT_ELEMS;
    hipLaunchKernelGGL(prep_kernel, dim3(512), dim3(256), 0, stream,
                       tanh_w, out_w, wt_hi, wt_lo, wo);
    hipLaunchKernelGGL(gru_main, dim3((NB / BM) * H8), dim3(NT), 0, stream,
                       x, h, sig_w, sig_b, tanh_b, out_b, wt_hi, wt_lo, wo,
                       out, out_nh);
  }
}

// Round 6
// 135.486 us; speedup vs baseline: 1.7134x; 1.0483x over previous
//
#include <hip/hip_runtime.h>
#include <math.h>

typedef short bf16x8 __attribute__((ext_vector_type(8)));
typedef short bf16x4 __attribute__((ext_vector_type(4)));
typedef float floatx4 __attribute__((ext_vector_type(4)));
typedef float floatx2 __attribute__((ext_vector_type(2)));
typedef float floatx16 __attribute__((ext_vector_type(16)));

#define NB   16384
#define H8   8
#define ND   256
#define NHD  128
#define NK   384

__device__ __forceinline__ unsigned short f2bf(float f) {
  unsigned int u = __float_as_uint(f);
  u += 0x7FFFu + ((u >> 16) & 1u);
  return (unsigned short)(u >> 16);
}
__device__ __forceinline__ float bf2f(unsigned short s) {
  return __uint_as_float(((unsigned int)s) << 16);
}
__device__ __forceinline__ float fast_sigmoid(float z) {
  z = fminf(fmaxf(z, -60.f), 60.f);
  return __builtin_amdgcn_rcpf(1.f + __expf(-z));
}
__device__ __forceinline__ float fast_tanh(float s) {
  s = fminf(fmaxf(s, -9.f), 9.f);
  float e = __expf(2.f * s);
  return (e - 1.f) * __builtin_amdgcn_rcpf(e + 1.f);
}

// ================= fragment-packed path (32x32x16) =================
#define WTP (H8 * 24 * 4 * 512)   // tanh_w frags (hi used; lo slot kept in ws layout)
#define WSP (H8 * 24 * 512)       // sig_w frags (cols 0,1 real)
#define WOP (H8 * 8 * 8 * 512)    // out_w frags
#define XFP (NB * ND)             // x frags (hi and lo)
#define WS_NEED3 ((size_t)(2 * WTP + 2 * WSP + WOP + 2 * XFP) * 2)

// blocks 0..191: tanh_w slab transpose (hi only); 192..255: out_w; rest: sig_w + x
__global__ void prep3b(const float* __restrict__ tanh_w,
                       const float* __restrict__ sig_w,
                       const float* __restrict__ out_w,
                       const float* __restrict__ x,
                       short* __restrict__ wtp_hi,
                       short* __restrict__ wsp_hi, short* __restrict__ wsp_lo,
                       short* __restrict__ wop,
                       short* __restrict__ xfh, short* __restrict__ xfl) {
  __shared__ float tile[16 * 260];
  const int t = threadIdx.x;
  const int b = blockIdx.x;
  if (b < 192) {
    int head = b / 24, ks = b % 24;
    const float* slab = tanh_w + ((size_t)head * NK + ks * 16) * NHD;
#pragma unroll
    for (int it = 0; it < 2; ++it) {
      int i = it * 256 + t;
      floatx4 v = reinterpret_cast<const floatx4*>(slab)[i];
      int r = i >> 5, c4 = i & 31;
      *reinterpret_cast<floatx4*>(&tile[r * 132 + c4 * 4]) = v;
    }
    __syncthreads();
    int ct = t >> 6, l = t & 63;
    bf16x8 hi8;
#pragma unroll
    for (int j = 0; j < 8; ++j) {
      float w = tile[((l >> 5) * 8 + j) * 132 + ct * 32 + (l & 31)];
      hi8[j] = (short)f2bf(w);
    }
    size_t dst = ((((size_t)head * 24 + ks) * 4 + ct) * 64 + l) * 8;
    *reinterpret_cast<bf16x8*>(wtp_hi + dst) = hi8;
  } else if (b < 256) {
    int head = (b - 192) / 8, ks = (b - 192) % 8;
    const float* slab = out_w + ((size_t)head * NHD + ks * 16) * ND;
#pragma unroll
    for (int it = 0; it < 4; ++it) {
      int i = it * 256 + t;
      floatx4 v = reinterpret_cast<const floatx4*>(slab)[i];
      int r = i >> 6, c4 = i & 63;
      *reinterpret_cast<floatx4*>(&tile[r * 260 + c4 * 4]) = v;
    }
    __syncthreads();
#pragma unroll
    for (int u = 0; u < 2; ++u) {
      int idx = u * 256 + t;
      int ct = idx >> 6, l = idx & 63;
      bf16x8 o8;
#pragma unroll
      for (int j = 0; j < 8; ++j) {
        float w = tile[((l >> 5) * 8 + j) * 260 + ct * 32 + (l & 31)];
        o8[j] = (short)f2bf(w);
      }
      size_t dst = ((((size_t)head * 8 + ks) * 8 + ct) * 64 + l) * 8;
      *reinterpret_cast<bf16x8*>(wop + dst) = o8;
    }
  } else {
    const int T2 = WSP, T3 = T2 + XFP;
    for (int i = (b - 256) * 256 + t; i < T3; i += (gridDim.x - 256) * 256) {
      if (i < T2) {
        int j = i & 7, l = (i >> 3) & 63;
        int q = i >> 9;
        int ks = q % 24, head = q / 24;
        int k = ks * 16 + (l >> 5) * 8 + j, n = l & 31;
        float w = (n < 2) ? sig_w[((size_t)head * NK + k) * 2 + n] : 0.f;
        unsigned short hi = f2bf(w);
        wsp_hi[i] = (short)hi;
        wsp_lo[i] = (short)f2bf(w - bf2f(hi));
      } else {
        int i4 = i - T2;
        int bb = i4 >> 8, c = i4 & 255;
        float v = x[i4];
        int dst = ((bb >> 5) * 16 + (c >> 4)) * 512 +
                  (((c >> 3) & 1) * 32 + (bb & 31)) * 8 + (c & 7);
        unsigned short hi = f2bf(v);
        xfh[dst] = (short)hi;
        xfl[dst] = (short)f2bf(v - bf2f(hi));
      }
    }
  }
}

// 256-thread block, 4 waves; wave = one 32-col quad (cq); BM=32 rows.
__global__ __launch_bounds__(256, 5) void gru3(
    const float* __restrict__ h, const float* __restrict__ sig_b,
    const float* __restrict__ tanh_b, const float* __restrict__ out_b,
    const short* __restrict__ wtp_hi,
    const short* __restrict__ wsp_hi, const short* __restrict__ wsp_lo,
    const short* __restrict__ wop,
    const short* __restrict__ xfh, const short* __restrict__ xfl,
    float* __restrict__ out, float* __restrict__ out_nh) {
  __shared__ __align__(16) short AhH[8 * 512];   // 8 KB h-hi frags -> new_h frags
  __shared__ __align__(16) short AhL[8 * 512];   // 8 KB h-lo frags
  __shared__ float sig_part[4 * 2 * 32];
  __shared__ float gbuf[32], pbuf[32];

  const int t = threadIdx.x;
  const int lane = t & 63;
  const int cq = t >> 6;          // 0..3
  const int l31 = lane & 31;
  const int lh = lane >> 5;
  const int head = (int)(blockIdx.x >> 9);
  const int rb = (int)(blockIdx.x & 511);
  const long rowbase = (long)rb * 32;

  // ---- stage h (32 rows x 128) into frag LDS, hi/lo ----
#pragma unroll
  for (int it = 0; it < 2; ++it) {
    int cidx = it * 256 + t;          // 0..511 chunks of 8
    int sks = cidx >> 6, sl = cidx & 63;
    int r = sl & 31;
    int k = sks * 16 + (sl >> 5) * 8;
    const float* hp = h + ((rowbase + r) * H8 + head) * NHD + k;
    floatx4 v0 = *reinterpret_cast<const floatx4*>(hp);
    floatx4 v1 = *reinterpret_cast<const floatx4*>(hp + 4);
    bf16x8 hi8, lo8;
#pragma unroll
    for (int j = 0; j < 4; ++j) {
      unsigned short hb = f2bf(v0[j]);
      hi8[j] = (short)hb; lo8[j] = (short)f2bf(v0[j] - bf2f(hb));
      unsigned short hb2 = f2bf(v1[j]);
      hi8[4 + j] = (short)hb2; lo8[4 + j] = (short)f2bf(v1[j] - bf2f(hb2));
    }
    *reinterpret_cast<bf16x8*>(&AhH[cidx * 8]) = hi8;
    *reinterpret_cast<bf16x8*>(&AhL[cidx * 8]) = lo8;
  }
  __syncthreads();

  // ---- K-loop: tanh 2-term (A hi+lo x B hi), sig 3-term ----
  floatx16 acc1, acc2, accS;
#pragma unroll
  for (int z = 0; z < 16; ++z) { acc1[z] = 0.f; acc2[z] = 0.f; accS[z] = 0.f; }

  const short* __restrict__ bh_p = wtp_hi + (((size_t)head * 24 * 4 + cq) * 512) + lane * 8;
  const short* __restrict__ sh_p = wsp_hi + ((size_t)head * 24 * 512) + lane * 8;
  const short* __restrict__ sl_p = wsp_lo + ((size_t)head * 24 * 512) + lane * 8;
  const short* __restrict__ xh_p = xfh + ((size_t)rb * 16 * 512) + lane * 8;
  const short* __restrict__ xl_p = xfl + ((size_t)rb * 16 * 512) + lane * 8;

  bf16x8 bh_n = *reinterpret_cast<const bf16x8*>(bh_p);
  bf16x8 ah_n, al_n;

#pragma unroll
  for (int ks = 0; ks < 8; ++ks) {
    bf16x8 bh = bh_n;
    bh_n = *reinterpret_cast<const bf16x8*>(bh_p + (ks + 1) * 2048);
    if (ks == 7) {
      ah_n = *reinterpret_cast<const bf16x8*>(xh_p);
      al_n = *reinterpret_cast<const bf16x8*>(xl_p);
    }
    bf16x8 ah = *reinterpret_cast<const bf16x8*>(&AhH[(ks * 64 + lane) * 8]);
    bf16x8 al = *reinterpret_cast<const bf16x8*>(&AhL[(ks * 64 + lane) * 8]);
    acc1 = __builtin_amdgcn_mfma_f32_32x32x16_bf16(ah, bh, acc1, 0, 0, 0);
    acc1 = __builtin_amdgcn_mfma_f32_32x32x16_bf16(al, bh, acc1, 0, 0, 0);
    if (ks / 6 == cq) {
      bf16x8 sh = *reinterpret_cast<const bf16x8*>(sh_p + ks * 512);
      bf16x8 sl2 = *reinterpret_cast<const bf16x8*>(sl_p + ks * 512);
      accS = __builtin_amdgcn_mfma_f32_32x32x16_bf16(ah, sh, accS, 0, 0, 0);
      accS = __builtin_amdgcn_mfma_f32_32x32x16_bf16(al, sh, accS, 0, 0, 0);
      accS = __builtin_amdgcn_mfma_f32_32x32x16_bf16(ah, sl2, accS, 0, 0, 0);
    }
  }
#pragma unroll
  for (int xks = 0; xks < 16; ++xks) {
    const int ks = 8 + xks;
    bf16x8 ah = ah_n, al = al_n;
    if (xks < 15) {
      ah_n = *reinterpret_cast<const bf16x8*>(xh_p + (xks + 1) * 512);
      al_n = *reinterpret_cast<const bf16x8*>(xl_p + (xks + 1) * 512);
    }
    bf16x8 bh = bh_n;
    if (ks < 23) bh_n = *reinterpret_cast<const bf16x8*>(bh_p + (ks + 1) * 2048);
    acc2 = __builtin_amdgcn_mfma_f32_32x32x16_bf16(ah, bh, acc2, 0, 0, 0);
    acc2 = __builtin_amdgcn_mfma_f32_32x32x16_bf16(al, bh, acc2, 0, 0, 0);
    if (ks / 6 == cq) {
      bf16x8 sh = *reinterpret_cast<const bf16x8*>(sh_p + ks * 512);
      bf16x8 sl2 = *reinterpret_cast<const bf16x8*>(sl_p + ks * 512);
      accS = __builtin_amdgcn_mfma_f32_32x32x16_bf16(ah, sh, accS, 0, 0, 0);
      accS = __builtin_amdgcn_mfma_f32_32x32x16_bf16(al, sh, accS, 0, 0, 0);
      accS = __builtin_amdgcn_mfma_f32_32x32x16_bf16(ah, sl2, accS, 0, 0, 0);
    }
  }

  // ---- sig partials -> reduce -> gates ----
  if (l31 < 2) {
#pragma unroll
    for (int reg = 0; reg < 16; ++reg) {
      int row = (reg & 3) + 8 * (reg >> 2) + 4 * lh;
      sig_part[(cq * 2 + l31) * 32 + row] = accS[reg];
    }
  }
  __syncthreads();
  if (t < 64) {
    int r = t >> 1, colc = t & 1;
    float z = sig_part[(0 * 2 + colc) * 32 + r] +
              sig_part[(1 * 2 + colc) * 32 + r] +
              sig_part[(2 * 2 + colc) * 32 + r] +
              sig_part[(3 * 2 + colc) * 32 + r] +
              sig_b[head * 2 + colc];
    float s = fast_sigmoid(z);
    if (colc == 0) gbuf[r] = s; else pbuf[r] = s;
  }
  __syncthreads();

  // ---- GRU epilogue (writes new_h frags into AhH in place) ----
  const int col = cq * 32 + l31;
  const float tb = tanh_b[head * NHD + col];
#pragma unroll
  for (int reg = 0; reg < 16; ++reg) {
    int r = (reg & 3) + 8 * (reg >> 2) + 4 * lh;
    float g = gbuf[r], p = pbuf[r];
    float s = g * acc1[reg] + acc2[reg] + tb;
    float cand = fast_tanh(s);
    int el = ((col >> 4) * 64 + ((l31 >> 3) & 1) * 32 + r) * 8 + (col & 7);
    float hv = bf2f((unsigned short)AhH[el]) + bf2f((unsigned short)AhL[el]);
    float nh = hv + p * (cand - hv);
    out_nh[((rowbase + r) * H8 + head) * NHD + col] = nh;
    AhH[el] = (short)f2bf(nh);
  }
  __syncthreads();

  // ---- out matmul: new_h (in AhH) @ out_w ----
  floatx16 acc3a, acc3b;
#pragma unroll
  for (int z = 0; z < 16; ++z) { acc3a[z] = 0.f; acc3b[z] = 0.f; }
  const short* __restrict__ wo_p = wop + (((size_t)head * 64 + cq * 2) * 512) + lane * 8;
  bf16x8 w0n = *reinterpret_cast<const bf16x8*>(wo_p);
  bf16x8 w1n = *reinterpret_cast<const bf16x8*>(wo_p + 512);
#pragma unroll
  for (int ks = 0; ks < 8; ++ks) {
    bf16x8 w0 = w0n, w1 = w1n;
    if (ks < 7) {
      w0n = *reinterpret_cast<const bf16x8*>(wo_p + (ks + 1) * 4096);
      w1n = *reinterpret_cast<const bf16x8*>(wo_p + (ks + 1) * 4096 + 512);
    }
    bf16x8 a = *reinterpret_cast<const bf16x8*>(&AhH[(ks * 64 + lane) * 8]);
    acc3a = __builtin_amdgcn_mfma_f32_32x32x16_bf16(a, w0, acc3a, 0, 0, 0);
    acc3b = __builtin_amdgcn_mfma_f32_32x32x16_bf16(a, w1, acc3b, 0, 0, 0);
  }
  const float ob0 = out_b[head * ND + cq * 64 + l31];
  const float ob1 = out_b[head * ND + cq * 64 + 32 + l31];
#pragma unroll
  for (int reg = 0; reg < 16; ++reg) {
    int r = (reg & 3) + 8 * (reg >> 2) + 4 * lh;
    long obase = ((rowbase + r) * H8 + head) * ND;
    out[obase + cq * 64 + l31] = acc3a[reg] + ob0;
    out[obase + cq * 64 + 32 + l31] = acc3b[reg] + ob1;
  }
}

// ================= fallback path (round-2 kernels) =================
#define WT_ELEMS (H8 * NK * NHD)
#define WO_ELEMS (H8 * NHD * ND)

__global__ void prep_kernel(const float* __restrict__ tanh_w,
                            const float* __restrict__ out_w,
                            short* __restrict__ wt_hi,
                            short* __restrict__ wt_lo,
                            short* __restrict__ wo) {
  const int total1 = WT_ELEMS;
  const int total2 = WO_ELEMS;
  for (int i = blockIdx.x * blockDim.x + threadIdx.x; i < total1 + total2;
       i += gridDim.x * blockDim.x) {
    if (i < total1) {
      int hh = i / (NK * NHD);
      int rem = i - hh * NK * NHD;
      int k = rem / NHD, n = rem - k * NHD;
      float w = tanh_w[i];
      unsigned short hi = f2bf(w);
      unsigned short lo = f2bf(w - bf2f(hi));
      int dst = hh * (48 * NHD * 8) + (k >> 3) * (NHD * 8) + n * 8 + (k & 7);
      wt_hi[dst] = (short)hi;
      wt_lo[dst] = (short)lo;
    } else {
      int j = i - total1;
      int hh = j / (NHD * ND);
      int rem = j - hh * NHD * ND;
      int k = rem / ND, n = rem - k * ND;
      int dst = hh * (16 * ND * 8) + (k >> 3) * (ND * 8) + n * 8 + (k & 7);
      wo[dst] = (short)f2bf(out_w[j]);
    }
  }
}

#define BM   32
#define NT   512
#define LDA 392
#define LDNH 136

__global__ __launch_bounds__(NT, 4) void gru_main(
    const float* __restrict__ x, const float* __restrict__ h,
    const float* __restrict__ sig_w, const float* __restrict__ sig_b,
    const float* __restrict__ tanh_b, const float* __restrict__ out_b,
    const short* __restrict__ wt_hi, const short* __restrict__ wt_lo,
    const short* __restrict__ wo,
    float* __restrict__ out, float* __restrict__ out_nh) {
  __shared__ __align__(16) short Ahi[BM][LDA];
  __shared__ __align__(16) short Alo[BM][LDA];
  __shared__ __align__(16) short NHL[BM][LDNH];
  __shared__ floatx2 swl[NK];
  __shared__ float gbuf[BM], pbuf[BM];

  const int t = threadIdx.x;
  const int lane = t & 63;
  const int wid = t >> 6;
  const int wrow = wid >> 2;
  const int wcol = wid & 3;
  const int ln = lane & 15;
  const int kg = lane >> 4;
  const int head = blockIdx.x & 7;
  const long rowbase = (long)(blockIdx.x >> 3) * BM;
  const int arow = wrow * 16 + ln;

#pragma unroll
  for (int i = 0; i < 4; ++i) {
    int idx = i * NT + t;
    int r = idx >> 6, c4 = idx & 63;
    floatx4 v = *reinterpret_cast<const floatx4*>(x + (rowbase + r) * ND + c4 * 4);
    bf16x4 hi, lo;
#pragma unroll
    for (int j = 0; j < 4; ++j) {
      unsigned short hb = f2bf(v[j]);
      hi[j] = (short)hb;
      lo[j] = (short)f2bf(v[j] - bf2f(hb));
    }
    *reinterpret_cast<bf16x4*>(&Ahi[r][NHD + c4 * 4]) = hi;
    *reinterpret_cast<bf16x4*>(&Alo[r][NHD + c4 * 4]) = lo;
  }
#pragma unroll
  for (int i = 0; i < 2; ++i) {
    int idx = i * NT + t;
    int r = idx >> 5, c4 = idx & 31;
    floatx4 v = *reinterpret_cast<const floatx4*>(
        h + ((rowbase + r) * H8 + head) * NHD + c4 * 4);
    bf16x4 hi, lo;
#pragma unroll
    for (int j = 0; j < 4; ++j) {
      unsigned short hb = f2bf(v[j]);
      hi[j] = (short)hb;
      lo[j] = (short)f2bf(v[j] - bf2f(hb));
    }
    *reinterpret_cast<bf16x4*>(&Ahi[r][c4 * 4]) = hi;
    *reinterpret_cast<bf16x4*>(&Alo[r][c4 * 4]) = lo;
  }
  if (t < NK)
    swl[t] = *reinterpret_cast<const floatx2*>(sig_w + ((size_t)head * NK + t) * 2);
  __syncthreads();
  {
    int r = t >> 4, u = t & 15;
    float a0 = 0.f, a1 = 0.f;
#pragma unroll
    for (int kk = 0; kk < 24; ++kk) {
      int k = u + kk * 16;
      float a = bf2f((unsigned short)Ahi[r][k]) + bf2f((unsigned short)Alo[r][k]);
      floatx2 w = swl[k];
      a0 += a * w[0];
      a1 += a * w[1];
    }
#pragma unroll
    for (int off = 1; off < 16; off <<= 1) {
      a0 += __shfl_xor(a0, off);
      a1 += __shfl_xor(a1, off);
    }
    if (u == 0) {
      gbuf[r] = fast_sigmoid(a0 + sig_b[head * 2 + 0]);
      pbuf[r] = fast_sigmoid(a1 + sig_b[head * 2 + 1]);
    }
  }
  floatx4 acc1[2] = {{0.f, 0.f, 0.f, 0.f}, {0.f, 0.f, 0.f, 0.f}};
  floatx4 acc2[2] = {{0.f, 0.f, 0.f, 0.f}, {0.f, 0.f, 0.f, 0.f}};
  const size_t wtbase = (size_t)head * (48 * NHD * 8);
#pragma unroll
  for (int ks = 0; ks < 12; ++ks) {
    bf16x8 ahi = *reinterpret_cast<const bf16x8*>(&Ahi[arow][ks * 32 + kg * 8]);
    bf16x8 alo = *reinterpret_cast<const bf16x8*>(&Alo[arow][ks * 32 + kg * 8]);
    floatx4* acc = (ks < 4) ? acc1 : acc2;
#pragma unroll
    for (int cf = 0; cf < 2; ++cf) {
      int n0 = wcol * 32 + cf * 16;
      size_t woff = wtbase + (size_t)(ks * 4 + kg) * (NHD * 8) + (size_t)(n0 + ln) * 8;
      bf16x8 bhi = *reinterpret_cast<const bf16x8*>(wt_hi + woff);
      bf16x8 blo = *reinterpret_cast<const bf16x8*>(wt_lo + woff);
      acc[cf] = __builtin_amdgcn_mfma_f32_16x16x32_bf16(ahi, bhi, acc[cf], 0, 0, 0);
      acc[cf] = __builtin_amdgcn_mfma_f32_16x16x32_bf16(alo, bhi, acc[cf], 0, 0, 0);
      acc[cf] = __builtin_amdgcn_mfma_f32_16x16x32_bf16(ahi, blo, acc[cf], 0, 0, 0);
    }
  }
  __syncthreads();
#pragma unroll
  for (int cf = 0; cf < 2; ++cf) {
    int col = wcol * 32 + cf * 16 + ln;
    float tb = tanh_b[head * NHD + col];
#pragma unroll
    for (int j = 0; j < 4; ++j) {
      int r = wrow * 16 + kg * 4 + j;
      float g = gbuf[r], p = pbuf[r];
      float s = g * acc1[cf][j] + acc2[cf][j] + tb;
      float cand = fast_tanh(s);
      float hv = bf2f((unsigned short)Ahi[r][col]) + bf2f((unsigned short)Alo[r][col]);
      float nh = hv + p * (cand - hv);
      out_nh[((rowbase + r) * H8 + head) * NHD + col] = nh;
      NHL[r][col] = (short)f2bf(nh);
    }
  }
  __syncthreads();
  floatx4 acc3[4] = {{0.f, 0.f, 0.f, 0.f}, {0.f, 0.f, 0.f, 0.f},
                     {0.f, 0.f, 0.f, 0.f}, {0.f, 0.f, 0.f, 0.f}};
  const size_t wobase = (size_t)head * (16 * ND * 8);
#pragma unroll
  for (int ks = 0; ks < 4; ++ks) {
    bf16x8 a = *reinterpret_cast<const bf16x8*>(&NHL[arow][ks * 32 + kg * 8]);
#pragma unroll
    for (int cf = 0; cf < 4; ++cf) {
      int n0 = wcol * 64 + cf * 16;
      size_t woff = wobase + (size_t)(ks * 4 + kg) * (ND * 8) + (size_t)(n0 + ln) * 8;
      bf16x8 bfr = *reinterpret_cast<const bf16x8*>(wo + woff);
      acc3[cf] = __builtin_amdgcn_mfma_f32_16x16x32_bf16(a, bfr, acc3[cf], 0, 0, 0);
    }
  }
#pragma unroll
  for (int cf = 0; cf < 4; ++cf) {
    int col = wcol * 64 + cf * 16 + ln;
    float ob = out_b[head * ND + col];
#pragma unroll
    for (int j = 0; j < 4; ++j) {
      int r = wrow * 16 + kg * 4 + j;
      out[((rowbase + r) * H8 + head) * ND + col] = acc3[cf][j] + ob;
    }
  }
}

extern "C" void kernel_launch(void* const* d_in, const int* in_sizes, int n_in,
                              void* d_out, int out_size, void* d_ws, size_t ws_size,
                              hipStream_t stream) {
  (void)in_sizes; (void)n_in; (void)out_size;
  const float* x      = (const float*)d_in[0];
  const float* h      = (const float*)d_in[1];
  const float* sig_w  = (const float*)d_in[2];
  const float* sig_b  = (const float*)d_in[3];
  const float* tanh_w = (const float*)d_in[4];
  const float* tanh_b = (const float*)d_in[5];
  const float* out_w  = (const float*)d_in[6];
  const float* out_b  = (const float*)d_in[7];

  float* out = (float*)d_out;
  float* out_nh = out + (size_t)NB * H8 * ND;

  if (ws_size >= WS_NEED3) {
    short* wtp_hi = (short*)d_ws;
    short* wtp_lo = wtp_hi + WTP;   // unused (layout keeps slot)
    short* wsp_hi = wtp_lo + WTP;
    short* wsp_lo = wsp_hi + WSP;
    short* wop    = wsp_lo + WSP;
    short* xfh    = wop + WOP;
    short* xfl    = xfh + XFP;
    hipLaunchKernelGGL(prep3b, dim3(256 + 1024), dim3(256), 0, stream,
                       tanh_w, sig_w, out_w, x,
                       wtp_hi, wsp_hi, wsp_lo, wop, xfh, xfl);
    hipLaunchKernelGGL(gru3, dim3((NB / 32) * H8), dim3(256), 0, stream,
                       h, sig_b, tanh_b, out_b,
                       wtp_hi, wsp_hi, wsp_lo, wop, xfh, xfl,
                       out, out_nh);
  } else {
    short* wt_hi = (short*)d_ws;
    short* wt_lo = wt_hi + WT_ELEMS;
    short* wo    = wt_lo + WT_ELEMS;
    hipLaunchKernelGGL(prep_kernel, dim3(512), dim3(256), 0, stream,
                       tanh_w, out_w, wt_hi, wt_lo, wo);
    hipLaunchKernelGGL(gru_main, dim3((NB / BM) * H8), dim3(NT), 0, stream,
                       x, h, sig_w, sig_b, tanh_b, out_b, wt_hi, wt_lo, wo,
                       out, out_nh);
  }
}

// Round 7
// 116.544 us; speedup vs baseline: 1.9918x; 1.1625x over previous
//
#include <hip/hip_runtime.h>
#include <math.h>

typedef short bf16x8 __attribute__((ext_vector_type(8)));
typedef short bf16x4 __attribute__((ext_vector_type(4)));
typedef float floatx4 __attribute__((ext_vector_type(4)));
typedef float floatx2 __attribute__((ext_vector_type(2)));
typedef float floatx16 __attribute__((ext_vector_type(16)));

#define NB   16384
#define H8   8
#define ND   256
#define NHD  128
#define NK   384

__device__ __forceinline__ unsigned short f2bf(float f) {
  unsigned int u = __float_as_uint(f);
  u += 0x7FFFu + ((u >> 16) & 1u);
  return (unsigned short)(u >> 16);
}
__device__ __forceinline__ float bf2f(unsigned short s) {
  return __uint_as_float(((unsigned int)s) << 16);
}
__device__ __forceinline__ float fast_sigmoid(float z) {
  z = fminf(fmaxf(z, -60.f), 60.f);
  return __builtin_amdgcn_rcpf(1.f + __expf(-z));
}
__device__ __forceinline__ float fast_tanh(float s) {
  s = fminf(fmaxf(s, -9.f), 9.f);
  float e = __expf(2.f * s);
  return (e - 1.f) * __builtin_amdgcn_rcpf(e + 1.f);
}

// ================= fragment-packed path (32x32x16) =================
#define WTP (H8 * 24 * 4 * 512)   // tanh_w frags (hi used; lo slot kept in ws layout)
#define WSP (H8 * 24 * 512)       // sig_w frags (cols 0,1 real)
#define WOP (H8 * 8 * 8 * 512)    // out_w frags
#define XFP (NB * ND)             // x frags (hi and lo)
#define WS_NEED3 ((size_t)(2 * WTP + 2 * WSP + WOP + 2 * XFP) * 2)

// blocks 0..191: tanh_w slab transpose (hi only); 192..255: out_w; rest: sig_w + x
__global__ void prep3b(const float* __restrict__ tanh_w,
                       const float* __restrict__ sig_w,
                       const float* __restrict__ out_w,
                       const float* __restrict__ x,
                       short* __restrict__ wtp_hi,
                       short* __restrict__ wsp_hi, short* __restrict__ wsp_lo,
                       short* __restrict__ wop,
                       short* __restrict__ xfh, short* __restrict__ xfl) {
  __shared__ float tile[16 * 260];
  const int t = threadIdx.x;
  const int b = blockIdx.x;
  if (b < 192) {
    int head = b / 24, ks = b % 24;
    const float* slab = tanh_w + ((size_t)head * NK + ks * 16) * NHD;
#pragma unroll
    for (int it = 0; it < 2; ++it) {
      int i = it * 256 + t;
      floatx4 v = reinterpret_cast<const floatx4*>(slab)[i];
      int r = i >> 5, c4 = i & 31;
      *reinterpret_cast<floatx4*>(&tile[r * 132 + c4 * 4]) = v;
    }
    __syncthreads();
    int ct = t >> 6, l = t & 63;
    bf16x8 hi8;
#pragma unroll
    for (int j = 0; j < 8; ++j) {
      float w = tile[((l >> 5) * 8 + j) * 132 + ct * 32 + (l & 31)];
      hi8[j] = (short)f2bf(w);
    }
    size_t dst = ((((size_t)head * 24 + ks) * 4 + ct) * 64 + l) * 8;
    *reinterpret_cast<bf16x8*>(wtp_hi + dst) = hi8;
  } else if (b < 256) {
    int head = (b - 192) / 8, ks = (b - 192) % 8;
    const float* slab = out_w + ((size_t)head * NHD + ks * 16) * ND;
#pragma unroll
    for (int it = 0; it < 4; ++it) {
      int i = it * 256 + t;
      floatx4 v = reinterpret_cast<const floatx4*>(slab)[i];
      int r = i >> 6, c4 = i & 63;
      *reinterpret_cast<floatx4*>(&tile[r * 260 + c4 * 4]) = v;
    }
    __syncthreads();
#pragma unroll
    for (int u = 0; u < 2; ++u) {
      int idx = u * 256 + t;
      int ct = idx >> 6, l = idx & 63;
      bf16x8 o8;
#pragma unroll
      for (int j = 0; j < 8; ++j) {
        float w = tile[((l >> 5) * 8 + j) * 260 + ct * 32 + (l & 31)];
        o8[j] = (short)f2bf(w);
      }
      size_t dst = ((((size_t)head * 8 + ks) * 8 + ct) * 64 + l) * 8;
      *reinterpret_cast<bf16x8*>(wop + dst) = o8;
    }
  } else {
    const int T2 = WSP;
    const int XQ = XFP / 4;          // x processed as float4 quads
    for (int i = (b - 256) * 256 + t; i < T2 + XQ; i += (gridDim.x - 256) * 256) {
      if (i < T2) {
        int j = i & 7, l = (i >> 3) & 63;
        int q = i >> 9;
        int ks = q % 24, head = q / 24;
        int k = ks * 16 + (l >> 5) * 8 + j, n = l & 31;
        float w = (n < 2) ? sig_w[((size_t)head * NK + k) * 2 + n] : 0.f;
        unsigned short hi = f2bf(w);
        wsp_hi[i] = (short)hi;
        wsp_lo[i] = (short)f2bf(w - bf2f(hi));
      } else {
        int q = i - T2;
        int bb = q >> 6, c0 = (q & 63) * 4;
        floatx4 v = *reinterpret_cast<const floatx4*>(x + (size_t)bb * ND + c0);
        bf16x4 h4, l4;
#pragma unroll
        for (int j = 0; j < 4; ++j) {
          unsigned short hb = f2bf(v[j]);
          h4[j] = (short)hb;
          l4[j] = (short)f2bf(v[j] - bf2f(hb));
        }
        int dst = ((bb >> 5) * 16 + (c0 >> 4)) * 512 +
                  (((c0 >> 3) & 1) * 32 + (bb & 31)) * 8 + (c0 & 7);
        *reinterpret_cast<bf16x4*>(xfh + dst) = h4;
        *reinterpret_cast<bf16x4*>(xfl + dst) = l4;
      }
    }
  }
}

// 256-thread block, 4 waves (one per 32-col quad cq); BM=64 rows = 2 row-groups/wave.
__global__ __launch_bounds__(256, 4) void gru3(
    const float* __restrict__ h, const float* __restrict__ sig_b,
    const float* __restrict__ tanh_b, const float* __restrict__ out_b,
    const short* __restrict__ wtp_hi,
    const short* __restrict__ wsp_hi, const short* __restrict__ wsp_lo,
    const short* __restrict__ wop,
    const short* __restrict__ xfh, const short* __restrict__ xfl,
    float* __restrict__ out, float* __restrict__ out_nh) {
  __shared__ __align__(16) short AhH[16 * 512];  // 16 KB: h-hi frags -> g*h hi -> new_h frags
  __shared__ __align__(16) short AhL[16 * 512];  // 16 KB: h-lo frags -> g*h lo
  __shared__ float sig_part[4 * 2 * 64];         // 2 KB
  __shared__ float gbuf[64], pbuf[64], ginv[64];

  const int t = threadIdx.x;
  const int lane = t & 63;
  const int cq = t >> 6;          // 0..3
  const int l31 = lane & 31;
  const int lh = lane >> 5;
  const int head = (int)(blockIdx.x >> 8);
  const int rb = (int)(blockIdx.x & 255);
  const long rowbase = (long)rb * 64;

  // ---- stage h (64 rows x 128) into frag LDS, hi/lo; 16 lanes per row (coalesced) ----
#pragma unroll
  for (int it = 0; it < 4; ++it) {
    int gi = it * 256 + t;            // 0..1023
    int row = gi >> 4, kc = gi & 15;  // kc: 8-float chunk within row
    const float* hp = h + ((rowbase + row) * H8 + head) * NHD + kc * 8;
    floatx4 v0 = *reinterpret_cast<const floatx4*>(hp);
    floatx4 v1 = *reinterpret_cast<const floatx4*>(hp + 4);
    bf16x8 hi8, lo8;
#pragma unroll
    for (int j = 0; j < 4; ++j) {
      unsigned short hb = f2bf(v0[j]);
      hi8[j] = (short)hb; lo8[j] = (short)f2bf(v0[j] - bf2f(hb));
      unsigned short hb2 = f2bf(v1[j]);
      hi8[4 + j] = (short)hb2; lo8[4 + j] = (short)f2bf(v1[j] - bf2f(hb2));
    }
    int rg = row >> 5, row32 = row & 31;
    int chunk = (rg * 8 + (kc >> 1)) * 64 + (kc & 1) * 32 + row32;
    *reinterpret_cast<bf16x8*>(&AhH[chunk * 8]) = hi8;
    *reinterpret_cast<bf16x8*>(&AhL[chunk * 8]) = lo8;
  }
  __syncthreads();

  const short* __restrict__ sh_p = wsp_hi + ((size_t)head * 24 * 512) + lane * 8;
  const short* __restrict__ sl_p = wsp_lo + ((size_t)head * 24 * 512) + lane * 8;
  const short* __restrict__ xh0 = xfh + ((size_t)(rb * 2 + 0) * 16 * 512) + lane * 8;
  const short* __restrict__ xl0 = xfl + ((size_t)(rb * 2 + 0) * 16 * 512) + lane * 8;
  const short* __restrict__ xh1 = xfh + ((size_t)(rb * 2 + 1) * 16 * 512) + lane * 8;
  const short* __restrict__ xl1 = xfl + ((size_t)(rb * 2 + 1) * 16 * 512) + lane * 8;

  // ---- sigmoid pass: each wave covers 6 K-slices for both row-groups ----
  {
    floatx16 accS0, accS1;
#pragma unroll
    for (int z = 0; z < 16; ++z) { accS0[z] = 0.f; accS1[z] = 0.f; }
#pragma unroll
    for (int i = 0; i < 6; ++i) {
      int ks = cq * 6 + i;
      bf16x8 sh = *reinterpret_cast<const bf16x8*>(sh_p + ks * 512);
      bf16x8 sl2 = *reinterpret_cast<const bf16x8*>(sl_p + ks * 512);
      bf16x8 a0h, a0l, a1h, a1l;
      if (ks < 8) {
        a0h = *reinterpret_cast<const bf16x8*>(&AhH[(ks * 64 + lane) * 8]);
        a0l = *reinterpret_cast<const bf16x8*>(&AhL[(ks * 64 + lane) * 8]);
        a1h = *reinterpret_cast<const bf16x8*>(&AhH[((8 + ks) * 64 + lane) * 8]);
        a1l = *reinterpret_cast<const bf16x8*>(&AhL[((8 + ks) * 64 + lane) * 8]);
      } else {
        int xk = ks - 8;
        a0h = *reinterpret_cast<const bf16x8*>(xh0 + xk * 512);
        a0l = *reinterpret_cast<const bf16x8*>(xl0 + xk * 512);
        a1h = *reinterpret_cast<const bf16x8*>(xh1 + xk * 512);
        a1l = *reinterpret_cast<const bf16x8*>(xl1 + xk * 512);
      }
      accS0 = __builtin_amdgcn_mfma_f32_32x32x16_bf16(a0h, sh, accS0, 0, 0, 0);
      accS0 = __builtin_amdgcn_mfma_f32_32x32x16_bf16(a0l, sh, accS0, 0, 0, 0);
      accS0 = __builtin_amdgcn_mfma_f32_32x32x16_bf16(a0h, sl2, accS0, 0, 0, 0);
      accS1 = __builtin_amdgcn_mfma_f32_32x32x16_bf16(a1h, sh, accS1, 0, 0, 0);
      accS1 = __builtin_amdgcn_mfma_f32_32x32x16_bf16(a1l, sh, accS1, 0, 0, 0);
      accS1 = __builtin_amdgcn_mfma_f32_32x32x16_bf16(a1h, sl2, accS1, 0, 0, 0);
    }
    if (l31 < 2) {
#pragma unroll
      for (int reg = 0; reg < 16; ++reg) {
        int crow = (reg & 3) + 8 * (reg >> 2) + 4 * lh;
        sig_part[(cq * 2 + l31) * 64 + crow] = accS0[reg];
        sig_part[(cq * 2 + l31) * 64 + 32 + crow] = accS1[reg];
      }
    }
  }
  __syncthreads();
  if (t < 128) {
    int r = t >> 1, colc = t & 1;
    float z = sig_part[(0 * 2 + colc) * 64 + r] +
              sig_part[(1 * 2 + colc) * 64 + r] +
              sig_part[(2 * 2 + colc) * 64 + r] +
              sig_part[(3 * 2 + colc) * 64 + r] +
              sig_b[head * 2 + colc];
    float s = fast_sigmoid(z);
    if (colc == 0) {
      gbuf[r] = s;
      ginv[r] = __builtin_amdgcn_rcpf(fmaxf(s, 1e-30f));
    } else pbuf[r] = s;
  }
  __syncthreads();

  // ---- rescale h frags in place: (hi,lo) <- split(g * (hi+lo)) ----
#pragma unroll
  for (int it = 0; it < 4; ++it) {
    int cidx = it * 256 + t;           // 0..1023 chunks
    int fidx = cidx >> 6, lanec = cidx & 63;
    int row = (fidx >> 3) * 32 + (lanec & 31);
    float g = gbuf[row];
    bf16x8 hi8 = *reinterpret_cast<const bf16x8*>(&AhH[cidx * 8]);
    bf16x8 lo8 = *reinterpret_cast<const bf16x8*>(&AhL[cidx * 8]);
    bf16x8 nh8, nl8;
#pragma unroll
    for (int j = 0; j < 8; ++j) {
      float hv = bf2f((unsigned short)hi8[j]) + bf2f((unsigned short)lo8[j]);
      float s = g * hv;
      unsigned short hb = f2bf(s);
      nh8[j] = (short)hb;
      nl8[j] = (short)f2bf(s - bf2f(hb));
    }
    *reinterpret_cast<bf16x8*>(&AhH[cidx * 8]) = nh8;
    *reinterpret_cast<bf16x8*>(&AhL[cidx * 8]) = nl8;
  }
  __syncthreads();

  // ---- tanh matmul: single acc per row-group; tanh_in = [g*h, x] ----
  floatx16 acc0, acc1;
#pragma unroll
  for (int z = 0; z < 16; ++z) { acc0[z] = 0.f; acc1[z] = 0.f; }
  const short* __restrict__ bh_p = wtp_hi + (((size_t)head * 24 * 4 + cq) * 512) + lane * 8;
  bf16x8 bh_n = *reinterpret_cast<const bf16x8*>(bh_p);
  bf16x8 a0h_n, a0l_n, a1h_n, a1l_n;
#pragma unroll
  for (int ks = 0; ks < 8; ++ks) {
    bf16x8 bh = bh_n;
    bh_n = *reinterpret_cast<const bf16x8*>(bh_p + (ks + 1) * 2048);
    if (ks == 7) {
      a0h_n = *reinterpret_cast<const bf16x8*>(xh0);
      a0l_n = *reinterpret_cast<const bf16x8*>(xl0);
      a1h_n = *reinterpret_cast<const bf16x8*>(xh1);
      a1l_n = *reinterpret_cast<const bf16x8*>(xl1);
    }
    bf16x8 a0h = *reinterpret_cast<const bf16x8*>(&AhH[(ks * 64 + lane) * 8]);
    bf16x8 a0l = *reinterpret_cast<const bf16x8*>(&AhL[(ks * 64 + lane) * 8]);
    bf16x8 a1h = *reinterpret_cast<const bf16x8*>(&AhH[((8 + ks) * 64 + lane) * 8]);
    bf16x8 a1l = *reinterpret_cast<const bf16x8*>(&AhL[((8 + ks) * 64 + lane) * 8]);
    acc0 = __builtin_amdgcn_mfma_f32_32x32x16_bf16(a0h, bh, acc0, 0, 0, 0);
    acc0 = __builtin_amdgcn_mfma_f32_32x32x16_bf16(a0l, bh, acc0, 0, 0, 0);
    acc1 = __builtin_amdgcn_mfma_f32_32x32x16_bf16(a1h, bh, acc1, 0, 0, 0);
    acc1 = __builtin_amdgcn_mfma_f32_32x32x16_bf16(a1l, bh, acc1, 0, 0, 0);
  }
#pragma unroll
  for (int xk = 0; xk < 16; ++xk) {
    const int ks = 8 + xk;
    bf16x8 a0h = a0h_n, a0l = a0l_n, a1h = a1h_n, a1l = a1l_n;
    if (xk < 15) {
      a0h_n = *reinterpret_cast<const bf16x8*>(xh0 + (xk + 1) * 512);
      a0l_n = *reinterpret_cast<const bf16x8*>(xl0 + (xk + 1) * 512);
      a1h_n = *reinterpret_cast<const bf16x8*>(xh1 + (xk + 1) * 512);
      a1l_n = *reinterpret_cast<const bf16x8*>(xl1 + (xk + 1) * 512);
    }
    bf16x8 bh = bh_n;
    if (ks < 23) bh_n = *reinterpret_cast<const bf16x8*>(bh_p + (ks + 1) * 2048);
    acc0 = __builtin_amdgcn_mfma_f32_32x32x16_bf16(a0h, bh, acc0, 0, 0, 0);
    acc0 = __builtin_amdgcn_mfma_f32_32x32x16_bf16(a0l, bh, acc0, 0, 0, 0);
    acc1 = __builtin_amdgcn_mfma_f32_32x32x16_bf16(a1h, bh, acc1, 0, 0, 0);
    acc1 = __builtin_amdgcn_mfma_f32_32x32x16_bf16(a1l, bh, acc1, 0, 0, 0);
  }
  __syncthreads();   // all scaled-frag LDS reads done before new_h overwrites

  // ---- GRU epilogue: cand = tanh(acc + b); h = (g*h)/g; new_h -> out_nh + LDS ----
  const int col = cq * 32 + l31;
  const float tb = tanh_b[head * NHD + col];
#define EPI(RG, ACC)                                                          \
  {                                                                           \
    _Pragma("unroll")                                                         \
    for (int reg = 0; reg < 16; ++reg) {                                      \
      int crow = (reg & 3) + 8 * (reg >> 2) + 4 * lh;                         \
      int row = RG * 32 + crow;                                               \
      float p = pbuf[row];                                                    \
      float cand = fast_tanh(ACC[reg] + tb);                                  \
      int el = ((RG * 8 + (col >> 4)) * 64 + ((l31 >> 3) & 1) * 32 + crow) * 8 + (col & 7); \
      float hv = (bf2f((unsigned short)AhH[el]) + bf2f((unsigned short)AhL[el])) * ginv[row]; \
      float nh = hv + p * (cand - hv);                                        \
      out_nh[((rowbase + row) * H8 + head) * NHD + col] = nh;                 \
      AhH[el] = (short)f2bf(nh);                                              \
    }                                                                         \
  }
  EPI(0, acc0)
  EPI(1, acc1)
#undef EPI
  __syncthreads();

  // ---- out matmul: new_h (in AhH) @ out_w, per row-group ----
  const short* __restrict__ wo_p = wop + (((size_t)head * 64 + cq * 2) * 512) + lane * 8;
  const float ob0 = out_b[head * ND + cq * 64 + l31];
  const float ob1 = out_b[head * ND + cq * 64 + 32 + l31];
#define OUTP(RG)                                                              \
  {                                                                           \
    floatx16 a3a, a3b;                                                        \
    _Pragma("unroll")                                                         \
    for (int z = 0; z < 16; ++z) { a3a[z] = 0.f; a3b[z] = 0.f; }              \
    bf16x8 w0n = *reinterpret_cast<const bf16x8*>(wo_p);                      \
    bf16x8 w1n = *reinterpret_cast<const bf16x8*>(wo_p + 512);                \
    _Pragma("unroll")                                                         \
    for (int ks = 0; ks < 8; ++ks) {                                          \
      bf16x8 w0 = w0n, w1 = w1n;                                              \
      if (ks < 7) {                                                           \
        w0n = *reinterpret_cast<const bf16x8*>(wo_p + (ks + 1) * 4096);       \
        w1n = *reinterpret_cast<const bf16x8*>(wo_p + (ks + 1) * 4096 + 512); \
      }                                                                       \
      bf16x8 a = *reinterpret_cast<const bf16x8*>(&AhH[((RG * 8 + ks) * 64 + lane) * 8]); \
      a3a = __builtin_amdgcn_mfma_f32_32x32x16_bf16(a, w0, a3a, 0, 0, 0);     \
      a3b = __builtin_amdgcn_mfma_f32_32x32x16_bf16(a, w1, a3b, 0, 0, 0);     \
    }                                                                         \
    _Pragma("unroll")                                                         \
    for (int reg = 0; reg < 16; ++reg) {                                      \
      int row = RG * 32 + (reg & 3) + 8 * (reg >> 2) + 4 * lh;                \
      long obase = ((rowbase + row) * H8 + head) * ND;                        \
      out[obase + cq * 64 + l31] = a3a[reg] + ob0;                            \
      out[obase + cq * 64 + 32 + l31] = a3b[reg] + ob1;                       \
    }                                                                         \
  }
  OUTP(0)
  OUTP(1)
#undef OUTP
}

// ================= fallback path (round-2 kernels) =================
#define WT_ELEMS (H8 * NK * NHD)
#define WO_ELEMS (H8 * NHD * ND)

__global__ void prep_kernel(const float* __restrict__ tanh_w,
                            const float* __restrict__ out_w,
                            short* __restrict__ wt_hi,
                            short* __restrict__ wt_lo,
                            short* __restrict__ wo) {
  const int total1 = WT_ELEMS;
  const int total2 = WO_ELEMS;
  for (int i = blockIdx.x * blockDim.x + threadIdx.x; i < total1 + total2;
       i += gridDim.x * blockDim.x) {
    if (i < total1) {
      int hh = i / (NK * NHD);
      int rem = i - hh * NK * NHD;
      int k = rem / NHD, n = rem - k * NHD;
      float w = tanh_w[i];
      unsigned short hi = f2bf(w);
      unsigned short lo = f2bf(w - bf2f(hi));
      int dst = hh * (48 * NHD * 8) + (k >> 3) * (NHD * 8) + n * 8 + (k & 7);
      wt_hi[dst] = (short)hi;
      wt_lo[dst] = (short)lo;
    } else {
      int j = i - total1;
      int hh = j / (NHD * ND);
      int rem = j - hh * NHD * ND;
      int k = rem / ND, n = rem - k * ND;
      int dst = hh * (16 * ND * 8) + (k >> 3) * (ND * 8) + n * 8 + (k & 7);
      wo[dst] = (short)f2bf(out_w[j]);
    }
  }
}

#define BM   32
#define NT   512
#define LDA 392
#define LDNH 136

__global__ __launch_bounds__(NT, 4) void gru_main(
    const float* __restrict__ x, const float* __restrict__ h,
    const float* __restrict__ sig_w, const float* __restrict__ sig_b,
    const float* __restrict__ tanh_b, const float* __restrict__ out_b,
    const short* __restrict__ wt_hi, const short* __restrict__ wt_lo,
    const short* __restrict__ wo,
    float* __restrict__ out, float* __restrict__ out_nh) {
  __shared__ __align__(16) short Ahi[BM][LDA];
  __shared__ __align__(16) short Alo[BM][LDA];
  __shared__ __align__(16) short NHL[BM][LDNH];
  __shared__ floatx2 swl[NK];
  __shared__ float gbuf[BM], pbuf[BM];

  const int t = threadIdx.x;
  const int lane = t & 63;
  const int wid = t >> 6;
  const int wrow = wid >> 2;
  const int wcol = wid & 3;
  const int ln = lane & 15;
  const int kg = lane >> 4;
  const int head = blockIdx.x & 7;
  const long rowbase = (long)(blockIdx.x >> 3) * BM;
  const int arow = wrow * 16 + ln;

#pragma unroll
  for (int i = 0; i < 4; ++i) {
    int idx = i * NT + t;
    int r = idx >> 6, c4 = idx & 63;
    floatx4 v = *reinterpret_cast<const floatx4*>(x + (rowbase + r) * ND + c4 * 4);
    bf16x4 hi, lo;
#pragma unroll
    for (int j = 0; j < 4; ++j) {
      unsigned short hb = f2bf(v[j]);
      hi[j] = (short)hb;
      lo[j] = (short)f2bf(v[j] - bf2f(hb));
    }
    *reinterpret_cast<bf16x4*>(&Ahi[r][NHD + c4 * 4]) = hi;
    *reinterpret_cast<bf16x4*>(&Alo[r][NHD + c4 * 4]) = lo;
  }
#pragma unroll
  for (int i = 0; i < 2; ++i) {
    int idx = i * NT + t;
    int r = idx >> 5, c4 = idx & 31;
    floatx4 v = *reinterpret_cast<const floatx4*>(
        h + ((rowbase + r) * H8 + head) * NHD + c4 * 4);
    bf16x4 hi, lo;
#pragma unroll
    for (int j = 0; j < 4; ++j) {
      unsigned short hb = f2bf(v[j]);
      hi[j] = (short)hb;
      lo[j] = (short)f2bf(v[j] - bf2f(hb));
    }
    *reinterpret_cast<bf16x4*>(&Ahi[r][c4 * 4]) = hi;
    *reinterpret_cast<bf16x4*>(&Alo[r][c4 * 4]) = lo;
  }
  if (t < NK)
    swl[t] = *reinterpret_cast<const floatx2*>(sig_w + ((size_t)head * NK + t) * 2);
  __syncthreads();
  {
    int r = t >> 4, u = t & 15;
    float a0 = 0.f, a1 = 0.f;
#pragma unroll
    for (int kk = 0; kk < 24; ++kk) {
      int k = u + kk * 16;
      float a = bf2f((unsigned short)Ahi[r][k]) + bf2f((unsigned short)Alo[r][k]);
      floatx2 w = swl[k];
      a0 += a * w[0];
      a1 += a * w[1];
    }
#pragma unroll
    for (int off = 1; off < 16; off <<= 1) {
      a0 += __shfl_xor(a0, off);
      a1 += __shfl_xor(a1, off);
    }
    if (u == 0) {
      gbuf[r] = fast_sigmoid(a0 + sig_b[head * 2 + 0]);
      pbuf[r] = fast_sigmoid(a1 + sig_b[head * 2 + 1]);
    }
  }
  floatx4 acc1[2] = {{0.f, 0.f, 0.f, 0.f}, {0.f, 0.f, 0.f, 0.f}};
  floatx4 acc2[2] = {{0.f, 0.f, 0.f, 0.f}, {0.f, 0.f, 0.f, 0.f}};
  const size_t wtbase = (size_t)head * (48 * NHD * 8);
#pragma unroll
  for (int ks = 0; ks < 12; ++ks) {
    bf16x8 ahi = *reinterpret_cast<const bf16x8*>(&Ahi[arow][ks * 32 + kg * 8]);
    bf16x8 alo = *reinterpret_cast<const bf16x8*>(&Alo[arow][ks * 32 + kg * 8]);
    floatx4* acc = (ks < 4) ? acc1 : acc2;
#pragma unroll
    for (int cf = 0; cf < 2; ++cf) {
      int n0 = wcol * 32 + cf * 16;
      size_t woff = wtbase + (size_t)(ks * 4 + kg) * (NHD * 8) + (size_t)(n0 + ln) * 8;
      bf16x8 bhi = *reinterpret_cast<const bf16x8*>(wt_hi + woff);
      bf16x8 blo = *reinterpret_cast<const bf16x8*>(wt_lo + woff);
      acc[cf] = __builtin_amdgcn_mfma_f32_16x16x32_bf16(ahi, bhi, acc[cf], 0, 0, 0);
      acc[cf] = __builtin_amdgcn_mfma_f32_16x16x32_bf16(alo, bhi, acc[cf], 0, 0, 0);
      acc[cf] = __builtin_amdgcn_mfma_f32_16x16x32_bf16(ahi, blo, acc[cf], 0, 0, 0);
    }
  }
  __syncthreads();
#pragma unroll
  for (int cf = 0; cf < 2; ++cf) {
    int col = wcol * 32 + cf * 16 + ln;
    float tb = tanh_b[head * NHD + col];
#pragma unroll
    for (int j = 0; j < 4; ++j) {
      int r = wrow * 16 + kg * 4 + j;
      float g = gbuf[r], p = pbuf[r];
      float s = g * acc1[cf][j] + acc2[cf][j] + tb;
      float cand = fast_tanh(s);
      float hv = bf2f((unsigned short)Ahi[r][col]) + bf2f((unsigned short)Alo[r][col]);
      float nh = hv + p * (cand - hv);
      out_nh[((rowbase + r) * H8 + head) * NHD + col] = nh;
      NHL[r][col] = (short)f2bf(nh);
    }
  }
  __syncthreads();
  floatx4 acc3[4] = {{0.f, 0.f, 0.f, 0.f}, {0.f, 0.f, 0.f, 0.f},
                     {0.f, 0.f, 0.f, 0.f}, {0.f, 0.f, 0.f, 0.f}};
  const size_t wobase = (size_t)head * (16 * ND * 8);
#pragma unroll
  for (int ks = 0; ks < 4; ++ks) {
    bf16x8 a = *reinterpret_cast<const bf16x8*>(&NHL[arow][ks * 32 + kg * 8]);
#pragma unroll
    for (int cf = 0; cf < 4; ++cf) {
      int n0 = wcol * 64 + cf * 16;
      size_t woff = wobase + (size_t)(ks * 4 + kg) * (ND * 8) + (size_t)(n0 + ln) * 8;
      bf16x8 bfr = *reinterpret_cast<const bf16x8*>(wo + woff);
      acc3[cf] = __builtin_amdgcn_mfma_f32_16x16x32_bf16(a, bfr, acc3[cf], 0, 0, 0);
    }
  }
#pragma unroll
  for (int cf = 0; cf < 4; ++cf) {
    int col = wcol * 64 + cf * 16 + ln;
    float ob = out_b[head * ND + col];
#pragma unroll
    for (int j = 0; j < 4; ++j) {
      int r = wrow * 16 + kg * 4 + j;
      out[((rowbase + r) * H8 + head) * ND + col] = acc3[cf][j] + ob;
    }
  }
}

extern "C" void kernel_launch(void* const* d_in, const int* in_sizes, int n_in,
                              void* d_out, int out_size, void* d_ws, size_t ws_size,
                              hipStream_t stream) {
  (void)in_sizes; (void)n_in; (void)out_size;
  const float* x      = (const float*)d_in[0];
  const float* h      = (const float*)d_in[1];
  const float* sig_w  = (const float*)d_in[2];
  const float* sig_b  = (const float*)d_in[3];
  const float* tanh_w = (const float*)d_in[4];
  const float* tanh_b = (const float*)d_in[5];
  const float* out_w  = (const float*)d_in[6];
  const float* out_b  = (const float*)d_in[7];

  float* out = (float*)d_out;
  float* out_nh = out + (size_t)NB * H8 * ND;

  if (ws_size >= WS_NEED3) {
    short* wtp_hi = (short*)d_ws;
    short* wtp_lo = wtp_hi + WTP;   // unused (layout keeps slot)
    short* wsp_hi = wtp_lo + WTP;
    short* wsp_lo = wsp_hi + WSP;
    short* wop    = wsp_lo + WSP;
    short* xfh    = wop + WOP;
    short* xfl    = xfh + XFP;
    hipLaunchKernelGGL(prep3b, dim3(256 + 2048), dim3(256), 0, stream,
                       tanh_w, sig_w, out_w, x,
                       wtp_hi, wsp_hi, wsp_lo, wop, xfh, xfl);
    hipLaunchKernelGGL(gru3, dim3((NB / 64) * H8), dim3(256), 0, stream,
                       h, sig_b, tanh_b, out_b,
                       wtp_hi, wsp_hi, wsp_lo, wop, xfh, xfl,
                       out, out_nh);
  } else {
    short* wt_hi = (short*)d_ws;
    short* wt_lo = wt_hi + WT_ELEMS;
    short* wo    = wt_lo + WT_ELEMS;
    hipLaunchKernelGGL(prep_kernel, dim3(512), dim3(256), 0, stream,
                       tanh_w, out_w, wt_hi, wt_lo, wo);
    hipLaunchKernelGGL(gru_main, dim3((NB / BM) * H8), dim3(NT), 0, stream,
                       x, h, sig_w, sig_b, tanh_b, out_b, wt_hi, wt_lo, wo,
                       out, out_nh);
  }
}

// Round 8
// 95.436 us; speedup vs baseline: 2.4324x; 1.2212x over previous
//
#include <hip/hip_runtime.h>
#include <math.h>

typedef short bf16x8 __attribute__((ext_vector_type(8)));
typedef short bf16x4 __attribute__((ext_vector_type(4)));
typedef float floatx4 __attribute__((ext_vector_type(4)));
typedef float floatx2 __attribute__((ext_vector_type(2)));
typedef float floatx16 __attribute__((ext_vector_type(16)));

#define NB   16384
#define H8   8
#define ND   256
#define NHD  128
#define NK   384

__device__ __forceinline__ unsigned short f2bf(float f) {
  unsigned int u = __float_as_uint(f);
  u += 0x7FFFu + ((u >> 16) & 1u);
  return (unsigned short)(u >> 16);
}
__device__ __forceinline__ float bf2f(unsigned short s) {
  return __uint_as_float(((unsigned int)s) << 16);
}
__device__ __forceinline__ float fast_sigmoid(float z) {
  z = fminf(fmaxf(z, -60.f), 60.f);
  return __builtin_amdgcn_rcpf(1.f + __expf(-z));
}
__device__ __forceinline__ float fast_tanh(float s) {
  s = fminf(fmaxf(s, -9.f), 9.f);
  float e = __expf(2.f * s);
  return (e - 1.f) * __builtin_amdgcn_rcpf(e + 1.f);
}

// ================= fragment-packed path (32x32x16) =================
#define WTP (H8 * 24 * 4 * 512)   // tanh_w frags (hi used; lo slot kept in ws layout)
#define WSP (H8 * 24 * 512)       // sig_w frags (cols 0,1 real)
#define WOP (H8 * 8 * 8 * 512)    // out_w frags
#define XFP (NB * ND)             // x frags (hi and lo)
#define WS_NEED3 ((size_t)(2 * WTP + 2 * WSP + WOP + 2 * XFP) * 2)

// blocks 0..191: tanh_w slab transpose (hi only); 192..255: out_w; rest: sig_w + x
__global__ void prep3b(const float* __restrict__ tanh_w,
                       const float* __restrict__ sig_w,
                       const float* __restrict__ out_w,
                       const float* __restrict__ x,
                       short* __restrict__ wtp_hi,
                       short* __restrict__ wsp_hi, short* __restrict__ wsp_lo,
                       short* __restrict__ wop,
                       short* __restrict__ xfh, short* __restrict__ xfl) {
  __shared__ float tile[16 * 260];
  const int t = threadIdx.x;
  const int b = blockIdx.x;
  if (b < 192) {
    int head = b / 24, ks = b % 24;
    const float* slab = tanh_w + ((size_t)head * NK + ks * 16) * NHD;
#pragma unroll
    for (int it = 0; it < 2; ++it) {
      int i = it * 256 + t;
      floatx4 v = reinterpret_cast<const floatx4*>(slab)[i];
      int r = i >> 5, c4 = i & 31;
      *reinterpret_cast<floatx4*>(&tile[r * 132 + c4 * 4]) = v;
    }
    __syncthreads();
    int ct = t >> 6, l = t & 63;
    bf16x8 hi8;
#pragma unroll
    for (int j = 0; j < 8; ++j) {
      float w = tile[((l >> 5) * 8 + j) * 132 + ct * 32 + (l & 31)];
      hi8[j] = (short)f2bf(w);
    }
    size_t dst = ((((size_t)head * 24 + ks) * 4 + ct) * 64 + l) * 8;
    *reinterpret_cast<bf16x8*>(wtp_hi + dst) = hi8;
  } else if (b < 256) {
    int head = (b - 192) / 8, ks = (b - 192) % 8;
    const float* slab = out_w + ((size_t)head * NHD + ks * 16) * ND;
#pragma unroll
    for (int it = 0; it < 4; ++it) {
      int i = it * 256 + t;
      floatx4 v = reinterpret_cast<const floatx4*>(slab)[i];
      int r = i >> 6, c4 = i & 63;
      *reinterpret_cast<floatx4*>(&tile[r * 260 + c4 * 4]) = v;
    }
    __syncthreads();
#pragma unroll
    for (int u = 0; u < 2; ++u) {
      int idx = u * 256 + t;
      int ct = idx >> 6, l = idx & 63;
      bf16x8 o8;
#pragma unroll
      for (int j = 0; j < 8; ++j) {
        float w = tile[((l >> 5) * 8 + j) * 260 + ct * 32 + (l & 31)];
        o8[j] = (short)f2bf(w);
      }
      size_t dst = ((((size_t)head * 8 + ks) * 8 + ct) * 64 + l) * 8;
      *reinterpret_cast<bf16x8*>(wop + dst) = o8;
    }
  } else {
    const int T2 = WSP;
    const int XQ8 = XFP / 8;         // 524288 8-float chunks
    for (int i = (b - 256) * 256 + t; i < T2 + XQ8; i += (gridDim.x - 256) * 256) {
      if (i < T2) {
        int j = i & 7, l = (i >> 3) & 63;
        int q = i >> 9;
        int ks = q % 24, head = q / 24;
        int k = ks * 16 + (l >> 5) * 8 + j, n = l & 31;
        float w = (n < 2) ? sig_w[((size_t)head * NK + k) * 2 + n] : 0.f;
        unsigned short hi = f2bf(w);
        wsp_hi[i] = (short)hi;
        wsp_lo[i] = (short)f2bf(w - bf2f(hi));
      } else {
        int q = i - T2;
        int bb = q >> 5, c0 = (q & 31) * 8;
        const float* xp = x + (size_t)bb * ND + c0;
        floatx4 v0 = *reinterpret_cast<const floatx4*>(xp);
        floatx4 v1 = *reinterpret_cast<const floatx4*>(xp + 4);
        bf16x8 h8, l8;
#pragma unroll
        for (int j = 0; j < 4; ++j) {
          unsigned short hb = f2bf(v0[j]);
          h8[j] = (short)hb; l8[j] = (short)f2bf(v0[j] - bf2f(hb));
          unsigned short hb2 = f2bf(v1[j]);
          h8[4 + j] = (short)hb2; l8[4 + j] = (short)f2bf(v1[j] - bf2f(hb2));
        }
        int dst = ((bb >> 5) * 16 + (c0 >> 4)) * 512 +
                  (((c0 >> 3) & 1) * 32 + (bb & 31)) * 8;
        *reinterpret_cast<bf16x8*>(xfh + dst) = h8;
        *reinterpret_cast<bf16x8*>(xfl + dst) = l8;
      }
    }
  }
}

// 256-thread block, 4 waves (one per 32-col quad cq); BM=64 rows = 2 row-groups/wave.
__global__ __launch_bounds__(256, 4) void gru3(
    const float* __restrict__ h, const float* __restrict__ sig_b,
    const float* __restrict__ tanh_b, const float* __restrict__ out_b,
    const short* __restrict__ wtp_hi,
    const short* __restrict__ wsp_hi, const short* __restrict__ wsp_lo,
    const short* __restrict__ wop,
    const short* __restrict__ xfh, const short* __restrict__ xfl,
    float* __restrict__ out, float* __restrict__ out_nh) {
  __shared__ __align__(16) short AhH[16 * 512];  // 16 KB: h-hi frags -> g*h hi -> new_h frags
  __shared__ __align__(16) short AhL[16 * 512];  // 16 KB: h-lo frags -> g*h lo
  __shared__ float sig_part[4 * 2 * 64];         // 2 KB
  __shared__ float gbuf[64], pbuf[64];

  const int t = threadIdx.x;
  const int lane = t & 63;
  const int cq = t >> 6;          // 0..3
  const int l31 = lane & 31;
  const int lh = lane >> 5;
  const int head = (int)(blockIdx.x >> 8);
  const int rb = (int)(blockIdx.x & 255);
  const long rowbase = (long)rb * 64;

  // ---- stage h (64 rows x 128) into frag LDS, hi/lo; 16 lanes per row (coalesced) ----
#pragma unroll
  for (int it = 0; it < 4; ++it) {
    int gi = it * 256 + t;            // 0..1023
    int row = gi >> 4, kc = gi & 15;  // kc: 8-float chunk within row
    const float* hp = h + ((rowbase + row) * H8 + head) * NHD + kc * 8;
    floatx4 v0 = *reinterpret_cast<const floatx4*>(hp);
    floatx4 v1 = *reinterpret_cast<const floatx4*>(hp + 4);
    bf16x8 hi8, lo8;
#pragma unroll
    for (int j = 0; j < 4; ++j) {
      unsigned short hb = f2bf(v0[j]);
      hi8[j] = (short)hb; lo8[j] = (short)f2bf(v0[j] - bf2f(hb));
      unsigned short hb2 = f2bf(v1[j]);
      hi8[4 + j] = (short)hb2; lo8[4 + j] = (short)f2bf(v1[j] - bf2f(hb2));
    }
    int rg = row >> 5, row32 = row & 31;
    int chunk = (rg * 8 + (kc >> 1)) * 64 + (kc & 1) * 32 + row32;
    *reinterpret_cast<bf16x8*>(&AhH[chunk * 8]) = hi8;
    *reinterpret_cast<bf16x8*>(&AhL[chunk * 8]) = lo8;
  }
  __syncthreads();

  const short* __restrict__ sh_p = wsp_hi + ((size_t)head * 24 * 512) + lane * 8;
  const short* __restrict__ sl_p = wsp_lo + ((size_t)head * 24 * 512) + lane * 8;
  const short* __restrict__ xh0 = xfh + ((size_t)(rb * 2 + 0) * 16 * 512) + lane * 8;
  const short* __restrict__ xl0 = xfl + ((size_t)(rb * 2 + 0) * 16 * 512) + lane * 8;
  const short* __restrict__ xh1 = xfh + ((size_t)(rb * 2 + 1) * 16 * 512) + lane * 8;
  const short* __restrict__ xl1 = xfl + ((size_t)(rb * 2 + 1) * 16 * 512) + lane * 8;

  // ---- sigmoid pass: 3-term, each wave covers 6 K-slices for both row-groups ----
  {
    floatx16 accS0, accS1;
#pragma unroll
    for (int z = 0; z < 16; ++z) { accS0[z] = 0.f; accS1[z] = 0.f; }
#pragma unroll
    for (int i = 0; i < 6; ++i) {
      int ks = cq * 6 + i;
      bf16x8 sh = *reinterpret_cast<const bf16x8*>(sh_p + ks * 512);
      bf16x8 sl2 = *reinterpret_cast<const bf16x8*>(sl_p + ks * 512);
      bf16x8 a0h, a0l, a1h, a1l;
      if (ks < 8) {
        a0h = *reinterpret_cast<const bf16x8*>(&AhH[(ks * 64 + lane) * 8]);
        a0l = *reinterpret_cast<const bf16x8*>(&AhL[(ks * 64 + lane) * 8]);
        a1h = *reinterpret_cast<const bf16x8*>(&AhH[((8 + ks) * 64 + lane) * 8]);
        a1l = *reinterpret_cast<const bf16x8*>(&AhL[((8 + ks) * 64 + lane) * 8]);
      } else {
        int xk = ks - 8;
        a0h = *reinterpret_cast<const bf16x8*>(xh0 + xk * 512);
        a0l = *reinterpret_cast<const bf16x8*>(xl0 + xk * 512);
        a1h = *reinterpret_cast<const bf16x8*>(xh1 + xk * 512);
        a1l = *reinterpret_cast<const bf16x8*>(xl1 + xk * 512);
      }
      accS0 = __builtin_amdgcn_mfma_f32_32x32x16_bf16(a0h, sh, accS0, 0, 0, 0);
      accS0 = __builtin_amdgcn_mfma_f32_32x32x16_bf16(a0l, sh, accS0, 0, 0, 0);
      accS0 = __builtin_amdgcn_mfma_f32_32x32x16_bf16(a0h, sl2, accS0, 0, 0, 0);
      accS1 = __builtin_amdgcn_mfma_f32_32x32x16_bf16(a1h, sh, accS1, 0, 0, 0);
      accS1 = __builtin_amdgcn_mfma_f32_32x32x16_bf16(a1l, sh, accS1, 0, 0, 0);
      accS1 = __builtin_amdgcn_mfma_f32_32x32x16_bf16(a1h, sl2, accS1, 0, 0, 0);
    }
    if (l31 < 2) {
#pragma unroll
      for (int reg = 0; reg < 16; ++reg) {
        int crow = (reg & 3) + 8 * (reg >> 2) + 4 * lh;
        sig_part[(cq * 2 + l31) * 64 + crow] = accS0[reg];
        sig_part[(cq * 2 + l31) * 64 + 32 + crow] = accS1[reg];
      }
    }
  }
  __syncthreads();
  if (t < 128) {
    int r = t >> 1, colc = t & 1;
    float z = sig_part[(0 * 2 + colc) * 64 + r] +
              sig_part[(1 * 2 + colc) * 64 + r] +
              sig_part[(2 * 2 + colc) * 64 + r] +
              sig_part[(3 * 2 + colc) * 64 + r] +
              sig_b[head * 2 + colc];
    float s = fast_sigmoid(z);
    if (colc == 0) gbuf[r] = s; else pbuf[r] = s;
  }
  __syncthreads();

  // ---- rescale h frags in place: (hi,lo) <- split(g * (hi+lo)) ----
#pragma unroll
  for (int it = 0; it < 4; ++it) {
    int cidx = it * 256 + t;           // 0..1023 chunks
    int fidx = cidx >> 6, lanec = cidx & 63;
    int row = (fidx >> 3) * 32 + (lanec & 31);
    float g = gbuf[row];
    bf16x8 hi8 = *reinterpret_cast<const bf16x8*>(&AhH[cidx * 8]);
    bf16x8 lo8 = *reinterpret_cast<const bf16x8*>(&AhL[cidx * 8]);
    bf16x8 nh8, nl8;
#pragma unroll
    for (int j = 0; j < 8; ++j) {
      float hv = bf2f((unsigned short)hi8[j]) + bf2f((unsigned short)lo8[j]);
      float s = g * hv;
      unsigned short hb = f2bf(s);
      nh8[j] = (short)hb;
      nl8[j] = (short)f2bf(s - bf2f(hb));
    }
    *reinterpret_cast<bf16x8*>(&AhH[cidx * 8]) = nh8;
    *reinterpret_cast<bf16x8*>(&AhL[cidx * 8]) = nl8;
  }
  __syncthreads();

  // ---- tanh matmul: single acc per row-group; tanh_in = [g*h (hi+lo), x (hi only)] ----
  floatx16 acc0, acc1;
#pragma unroll
  for (int z = 0; z < 16; ++z) { acc0[z] = 0.f; acc1[z] = 0.f; }
  const short* __restrict__ bh_p = wtp_hi + (((size_t)head * 24 * 4 + cq) * 512) + lane * 8;

  // h-part: ks 0..7, A from LDS, B 2-deep prefetch
  bf16x8 bhA = *reinterpret_cast<const bf16x8*>(bh_p);
  bf16x8 bhB = *reinterpret_cast<const bf16x8*>(bh_p + 2048);
#pragma unroll
  for (int ks = 0; ks < 8; ++ks) {
    bf16x8 bh = bhA; bhA = bhB;
    bhB = *reinterpret_cast<const bf16x8*>(bh_p + (ks + 2) * 2048);
    bf16x8 a0h = *reinterpret_cast<const bf16x8*>(&AhH[(ks * 64 + lane) * 8]);
    bf16x8 a0l = *reinterpret_cast<const bf16x8*>(&AhL[(ks * 64 + lane) * 8]);
    bf16x8 a1h = *reinterpret_cast<const bf16x8*>(&AhH[((8 + ks) * 64 + lane) * 8]);
    bf16x8 a1l = *reinterpret_cast<const bf16x8*>(&AhL[((8 + ks) * 64 + lane) * 8]);
    acc0 = __builtin_amdgcn_mfma_f32_32x32x16_bf16(a0h, bh, acc0, 0, 0, 0);
    acc0 = __builtin_amdgcn_mfma_f32_32x32x16_bf16(a0l, bh, acc0, 0, 0, 0);
    acc1 = __builtin_amdgcn_mfma_f32_32x32x16_bf16(a1h, bh, acc1, 0, 0, 0);
    acc1 = __builtin_amdgcn_mfma_f32_32x32x16_bf16(a1l, bh, acc1, 0, 0, 0);
  }
  // x-part: ks 8..23, x-hi only, 2-deep prefetch on both streams
  {
    bf16x8 x0A = *reinterpret_cast<const bf16x8*>(xh0);
    bf16x8 x1A = *reinterpret_cast<const bf16x8*>(xh1);
    bf16x8 x0B = *reinterpret_cast<const bf16x8*>(xh0 + 512);
    bf16x8 x1B = *reinterpret_cast<const bf16x8*>(xh1 + 512);
#pragma unroll
    for (int xk = 0; xk < 16; ++xk) {
      const int ks = 8 + xk;
      bf16x8 bh = bhA; bhA = bhB;
      if (ks + 2 < 24) bhB = *reinterpret_cast<const bf16x8*>(bh_p + (ks + 2) * 2048);
      bf16x8 x0 = x0A, x1 = x1A;
      x0A = x0B; x1A = x1B;
      if (xk + 2 < 16) {
        x0B = *reinterpret_cast<const bf16x8*>(xh0 + (xk + 2) * 512);
        x1B = *reinterpret_cast<const bf16x8*>(xh1 + (xk + 2) * 512);
      }
      acc0 = __builtin_amdgcn_mfma_f32_32x32x16_bf16(x0, bh, acc0, 0, 0, 0);
      acc1 = __builtin_amdgcn_mfma_f32_32x32x16_bf16(x1, bh, acc1, 0, 0, 0);
    }
  }
  __syncthreads();   // all scaled-frag LDS reads done before new_h overwrites

  // ---- GRU epilogue: cand = tanh(acc + b); hv re-read from h (L2-warm, coalesced) ----
  const int col = cq * 32 + l31;
  const float tb = tanh_b[head * NHD + col];
  const float* __restrict__ hcol = h + (rowbase * H8 + head) * NHD + col;
#define EPI(RG, ACC)                                                          \
  {                                                                           \
    _Pragma("unroll")                                                         \
    for (int reg = 0; reg < 16; ++reg) {                                      \
      int crow = (reg & 3) + 8 * (reg >> 2) + 4 * lh;                         \
      int row = RG * 32 + crow;                                               \
      float p = pbuf[row];                                                    \
      float cand = fast_tanh(ACC[reg] + tb);                                  \
      float hv = hcol[(size_t)row * (H8 * NHD)];                              \
      float nh = hv + p * (cand - hv);                                        \
      int el = ((RG * 8 + (col >> 4)) * 64 + ((l31 >> 3) & 1) * 32 + crow) * 8 + (col & 7); \
      out_nh[((rowbase + row) * H8 + head) * NHD + col] = nh;                 \
      AhH[el] = (short)f2bf(nh);                                              \
    }                                                                         \
  }
  EPI(0, acc0)
  EPI(1, acc1)
#undef EPI
  __syncthreads();

  // ---- out matmul: new_h (in AhH) @ out_w, per row-group ----
  const short* __restrict__ wo_p = wop + (((size_t)head * 64 + cq * 2) * 512) + lane * 8;
  const float ob0 = out_b[head * ND + cq * 64 + l31];
  const float ob1 = out_b[head * ND + cq * 64 + 32 + l31];
#define OUTP(RG)                                                              \
  {                                                                           \
    floatx16 a3a, a3b;                                                        \
    _Pragma("unroll")                                                         \
    for (int z = 0; z < 16; ++z) { a3a[z] = 0.f; a3b[z] = 0.f; }              \
    bf16x8 w0n = *reinterpret_cast<const bf16x8*>(wo_p);                      \
    bf16x8 w1n = *reinterpret_cast<const bf16x8*>(wo_p + 512);                \
    _Pragma("unroll")                                                         \
    for (int ks = 0; ks < 8; ++ks) {                                          \
      bf16x8 w0 = w0n, w1 = w1n;                                              \
      if (ks < 7) {                                                           \
        w0n = *reinterpret_cast<const bf16x8*>(wo_p + (ks + 1) * 4096);       \
        w1n = *reinterpret_cast<const bf16x8*>(wo_p + (ks + 1) * 4096 + 512); \
      }                                                                       \
      bf16x8 a = *reinterpret_cast<const bf16x8*>(&AhH[((RG * 8 + ks) * 64 + lane) * 8]); \
      a3a = __builtin_amdgcn_mfma_f32_32x32x16_bf16(a, w0, a3a, 0, 0, 0);     \
      a3b = __builtin_amdgcn_mfma_f32_32x32x16_bf16(a, w1, a3b, 0, 0, 0);     \
    }                                                                         \
    _Pragma("unroll")                                                         \
    for (int reg = 0; reg < 16; ++reg) {                                      \
      int row = RG * 32 + (reg & 3) + 8 * (reg >> 2) + 4 * lh;                \
      long obase = ((rowbase + row) * H8 + head) * ND;                        \
      out[obase + cq * 64 + l31] = a3a[reg] + ob0;                            \
      out[obase + cq * 64 + 32 + l31] = a3b[reg] + ob1;                       \
    }                                                                         \
  }
  OUTP(0)
  OUTP(1)
#undef OUTP
}

// ================= fallback path (round-2 kernels) =================
#define WT_ELEMS (H8 * NK * NHD)
#define WO_ELEMS (H8 * NHD * ND)

__global__ void prep_kernel(const float* __restrict__ tanh_w,
                            const float* __restrict__ out_w,
                            short* __restrict__ wt_hi,
                            short* __restrict__ wt_lo,
                            short* __restrict__ wo) {
  const int total1 = WT_ELEMS;
  const int total2 = WO_ELEMS;
  for (int i = blockIdx.x * blockDim.x + threadIdx.x; i < total1 + total2;
       i += gridDim.x * blockDim.x) {
    if (i < total1) {
      int hh = i / (NK * NHD);
      int rem = i - hh * NK * NHD;
      int k = rem / NHD, n = rem - k * NHD;
      float w = tanh_w[i];
      unsigned short hi = f2bf(w);
      unsigned short lo = f2bf(w - bf2f(hi));
      int dst = hh * (48 * NHD * 8) + (k >> 3) * (NHD * 8) + n * 8 + (k & 7);
      wt_hi[dst] = (short)hi;
      wt_lo[dst] = (short)lo;
    } else {
      int j = i - total1;
      int hh = j / (NHD * ND);
      int rem = j - hh * NHD * ND;
      int k = rem / ND, n = rem - k * ND;
      int dst = hh * (16 * ND * 8) + (k >> 3) * (ND * 8) + n * 8 + (k & 7);
      wo[dst] = (short)f2bf(out_w[j]);
    }
  }
}

#define BM   32
#define NT   512
#define LDA 392
#define LDNH 136

__global__ __launch_bounds__(NT, 4) void gru_main(
    const float* __restrict__ x, const float* __restrict__ h,
    const float* __restrict__ sig_w, const float* __restrict__ sig_b,
    const float* __restrict__ tanh_b, const float* __restrict__ out_b,
    const short* __restrict__ wt_hi, const short* __restrict__ wt_lo,
    const short* __restrict__ wo,
    float* __restrict__ out, float* __restrict__ out_nh) {
  __shared__ __align__(16) short Ahi[BM][LDA];
  __shared__ __align__(16) short Alo[BM][LDA];
  __shared__ __align__(16) short NHL[BM][LDNH];
  __shared__ floatx2 swl[NK];
  __shared__ float gbuf[BM], pbuf[BM];

  const int t = threadIdx.x;
  const int lane = t & 63;
  const int wid = t >> 6;
  const int wrow = wid >> 2;
  const int wcol = wid & 3;
  const int ln = lane & 15;
  const int kg = lane >> 4;
  const int head = blockIdx.x & 7;
  const long rowbase = (long)(blockIdx.x >> 3) * BM;
  const int arow = wrow * 16 + ln;

#pragma unroll
  for (int i = 0; i < 4; ++i) {
    int idx = i * NT + t;
    int r = idx >> 6, c4 = idx & 63;
    floatx4 v = *reinterpret_cast<const floatx4*>(x + (rowbase + r) * ND + c4 * 4);
    bf16x4 hi, lo;
#pragma unroll
    for (int j = 0; j < 4; ++j) {
      unsigned short hb = f2bf(v[j]);
      hi[j] = (short)hb;
      lo[j] = (short)f2bf(v[j] - bf2f(hb));
    }
    *reinterpret_cast<bf16x4*>(&Ahi[r][NHD + c4 * 4]) = hi;
    *reinterpret_cast<bf16x4*>(&Alo[r][NHD + c4 * 4]) = lo;
  }
#pragma unroll
  for (int i = 0; i < 2; ++i) {
    int idx = i * NT + t;
    int r = idx >> 5, c4 = idx & 31;
    floatx4 v = *reinterpret_cast<const floatx4*>(
        h + ((rowbase + r) * H8 + head) * NHD + c4 * 4);
    bf16x4 hi, lo;
#pragma unroll
    for (int j = 0; j < 4; ++j) {
      unsigned short hb = f2bf(v[j]);
      hi[j] = (short)hb;
      lo[j] = (short)f2bf(v[j] - bf2f(hb));
    }
    *reinterpret_cast<bf16x4*>(&Ahi[r][c4 * 4]) = hi;
    *reinterpret_cast<bf16x4*>(&Alo[r][c4 * 4]) = lo;
  }
  if (t < NK)
    swl[t] = *reinterpret_cast<const floatx2*>(sig_w + ((size_t)head * NK + t) * 2);
  __syncthreads();
  {
    int r = t >> 4, u = t & 15;
    float a0 = 0.f, a1 = 0.f;
#pragma unroll
    for (int kk = 0; kk < 24; ++kk) {
      int k = u + kk * 16;
      float a = bf2f((unsigned short)Ahi[r][k]) + bf2f((unsigned short)Alo[r][k]);
      floatx2 w = swl[k];
      a0 += a * w[0];
      a1 += a * w[1];
    }
#pragma unroll
    for (int off = 1; off < 16; off <<= 1) {
      a0 += __shfl_xor(a0, off);
      a1 += __shfl_xor(a1, off);
    }
    if (u == 0) {
      gbuf[r] = fast_sigmoid(a0 + sig_b[head * 2 + 0]);
      pbuf[r] = fast_sigmoid(a1 + sig_b[head * 2 + 1]);
    }
  }
  floatx4 acc1[2] = {{0.f, 0.f, 0.f, 0.f}, {0.f, 0.f, 0.f, 0.f}};
  floatx4 acc2[2] = {{0.f, 0.f, 0.f, 0.f}, {0.f, 0.f, 0.f, 0.f}};
  const size_t wtbase = (size_t)head * (48 * NHD * 8);
#pragma unroll
  for (int ks = 0; ks < 12; ++ks) {
    bf16x8 ahi = *reinterpret_cast<const bf16x8*>(&Ahi[arow][ks * 32 + kg * 8]);
    bf16x8 alo = *reinterpret_cast<const bf16x8*>(&Alo[arow][ks * 32 + kg * 8]);
    floatx4* acc = (ks < 4) ? acc1 : acc2;
#pragma unroll
    for (int cf = 0; cf < 2; ++cf) {
      int n0 = wcol * 32 + cf * 16;
      size_t woff = wtbase + (size_t)(ks * 4 + kg) * (NHD * 8) + (size_t)(n0 + ln) * 8;
      bf16x8 bhi = *reinterpret_cast<const bf16x8*>(wt_hi + woff);
      bf16x8 blo = *reinterpret_cast<const bf16x8*>(wt_lo + woff);
      acc[cf] = __builtin_amdgcn_mfma_f32_16x16x32_bf16(ahi, bhi, acc[cf], 0, 0, 0);
      acc[cf] = __builtin_amdgcn_mfma_f32_16x16x32_bf16(alo, bhi, acc[cf], 0, 0, 0);
      acc[cf] = __builtin_amdgcn_mfma_f32_16x16x32_bf16(ahi, blo, acc[cf], 0, 0, 0);
    }
  }
  __syncthreads();
#pragma unroll
  for (int cf = 0; cf < 2; ++cf) {
    int col = wcol * 32 + cf * 16 + ln;
    float tb = tanh_b[head * NHD + col];
#pragma unroll
    for (int j = 0; j < 4; ++j) {
      int r = wrow * 16 + kg * 4 + j;
      float g = gbuf[r], p = pbuf[r];
      float s = g * acc1[cf][j] + acc2[cf][j] + tb;
      float cand = fast_tanh(s);
      float hv = bf2f((unsigned short)Ahi[r][col]) + bf2f((unsigned short)Alo[r][col]);
      float nh = hv + p * (cand - hv);
      out_nh[((rowbase + r) * H8 + head) * NHD + col] = nh;
      NHL[r][col] = (short)f2bf(nh);
    }
  }
  __syncthreads();
  floatx4 acc3[4] = {{0.f, 0.f, 0.f, 0.f}, {0.f, 0.f, 0.f, 0.f},
                     {0.f, 0.f, 0.f, 0.f}, {0.f, 0.f, 0.f, 0.f}};
  const size_t wobase = (size_t)head * (16 * ND * 8);
#pragma unroll
  for (int ks = 0; ks < 4; ++ks) {
    bf16x8 a = *reinterpret_cast<const bf16x8*>(&NHL[arow][ks * 32 + kg * 8]);
#pragma unroll
    for (int cf = 0; cf < 4; ++cf) {
      int n0 = wcol * 64 + cf * 16;
      size_t woff = wobase + (size_t)(ks * 4 + kg) * (ND * 8) + (size_t)(n0 + ln) * 8;
      bf16x8 bfr = *reinterpret_cast<const bf16x8*>(wo + woff);
      acc3[cf] = __builtin_amdgcn_mfma_f32_16x16x32_bf16(a, bfr, acc3[cf], 0, 0, 0);
    }
  }
#pragma unroll
  for (int cf = 0; cf < 4; ++cf) {
    int col = wcol * 64 + cf * 16 + ln;
    float ob = out_b[head * ND + col];
#pragma unroll
    for (int j = 0; j < 4; ++j) {
      int r = wrow * 16 + kg * 4 + j;
      out[((rowbase + r) * H8 + head) * ND + col] = acc3[cf][j] + ob;
    }
  }
}

extern "C" void kernel_launch(void* const* d_in, const int* in_sizes, int n_in,
                              void* d_out, int out_size, void* d_ws, size_t ws_size,
                              hipStream_t stream) {
  (void)in_sizes; (void)n_in; (void)out_size;
  const float* x      = (const float*)d_in[0];
  const float* h      = (const float*)d_in[1];
  const float* sig_w  = (const float*)d_in[2];
  const float* sig_b  = (const float*)d_in[3];
  const float* tanh_w = (const float*)d_in[4];
  const float* tanh_b = (const float*)d_in[5];
  const float* out_w  = (const float*)d_in[6];
  const float* out_b  = (const float*)d_in[7];

  float* out = (float*)d_out;
  float* out_nh = out + (size_t)NB * H8 * ND;

  if (ws_size >= WS_NEED3) {
    short* wtp_hi = (short*)d_ws;
    short* wtp_lo = wtp_hi + WTP;   // unused (layout keeps slot)
    short* wsp_hi = wtp_lo + WTP;
    short* wsp_lo = wsp_hi + WSP;
    short* wop    = wsp_lo + WSP;
    short* xfh    = wop + WOP;
    short* xfl    = xfh + XFP;
    hipLaunchKernelGGL(prep3b, dim3(256 + 2432), dim3(256), 0, stream,
                       tanh_w, sig_w, out_w, x,
                       wtp_hi, wsp_hi, wsp_lo, wop, xfh, xfl);
    hipLaunchKernelGGL(gru3, dim3((NB / 64) * H8), dim3(256), 0, stream,
                       h, sig_b, tanh_b, out_b,
                       wtp_hi, wsp_hi, wsp_lo, wop, xfh, xfl,
                       out, out_nh);
  } else {
    short* wt_hi = (short*)d_ws;
    short* wt_lo = wt_hi + WT_ELEMS;
    short* wo    = wt_lo + WT_ELEMS;
    hipLaunchKernelGGL(prep_kernel, dim3(512), dim3(256), 0, stream,
                       tanh_w, out_w, wt_hi, wt_lo, wo);
    hipLaunchKernelGGL(gru_main, dim3((NB / BM) * H8), dim3(NT), 0, stream,
                       x, h, sig_w, sig_b, tanh_b, out_b, wt_hi, wt_lo, wo,
                       out, out_nh);
  }
}